// Round 14
// baseline (300.793 us; speedup 1.0000x reference)
//
#include <hip/hip_runtime.h>
#include <math.h>

// 3-layer GAT. Round 14: R12 structure, but gemm_fill_fused puts FILL blocks
// first (blockIdx 0..FILLB-1) and GEMM blocks after: with in-order block
// dispatch the GEMM compute streams in behind the memory-stalled fill blocks
// and overlaps the fill tail. R13's interleave reverted; gather40 quad-unroll
// kept. Quad-unrolled gather128, col-block-looped GEMM, fused prep.

#define HEADS 4
#define FILLB 4096
#define FILL_U 4

typedef __attribute__((ext_vector_type(8))) short short8v;   // 8 bf16
typedef __attribute__((ext_vector_type(4))) float float4v;   // 4 fp32 acc

__device__ __forceinline__ float lrelu(float v) { return v > 0.f ? v : 0.2f * v; }

__device__ __forceinline__ unsigned short f2bf(float f) {
    unsigned u = __float_as_uint(f);
    unsigned r = u + 0x7FFFu + ((u >> 16) & 1u);   // RNE
    return (unsigned short)(r >> 16);
}
__device__ __forceinline__ float bf2f(unsigned short u) {
    return __uint_as_float(((unsigned)u) << 16);
}

// ---------------- device bodies ----------------
__device__ void castX_body(const float* __restrict__ x, unsigned short* __restrict__ xb,
                           int n4, int i) {
    if (i >= n4) return;
    float4 v = *(const float4*)&x[(size_t)i * 4];
    ushort4 o;
    o.x = f2bf(v.x); o.y = f2bf(v.y); o.z = f2bf(v.z); o.w = f2bf(v.w);
    *(ushort4*)&xb[(size_t)i * 4] = o;
}

__device__ void hist_body(const int* __restrict__ dst, int E, int* __restrict__ deg, int t) {
    int e = t * 4;
    if (e + 3 < E) {
        int4 d = *(const int4*)&dst[e];
        atomicAdd(&deg[d.x], 1);
        atomicAdd(&deg[d.y], 1);
        atomicAdd(&deg[d.z], 1);
        atomicAdd(&deg[d.w], 1);
    } else {
        for (; e < E; ++e) atomicAdd(&deg[dst[e]], 1);
    }
}

// BT12: (256+64) rows x 128 k. rows 0..127 = W, 128..255 = LW, 256..259 = W@a_s,
// 260..263 = W@a_d, rest 0.
__device__ void packB12_body(const float* __restrict__ W, const float* __restrict__ LW,
                             const float* __restrict__ a_s, const float* __restrict__ a_d,
                             unsigned short* __restrict__ BT, int i) {
    if (i >= 320 * 128) return;
    int m = i >> 7, k = i & 127;
    float v = 0.f;
    if (m < 128) {
        v = W[(size_t)k * 128 + m];
    } else if (m < 256) {
        v = LW[(size_t)k * 128 + (m - 128)];
    } else if (m < 260) {
        int h = m - 256;
        for (int c = 0; c < 32; ++c)
            v = fmaf(W[(size_t)k * 128 + h * 32 + c], a_s[h * 32 + c], v);
    } else if (m < 264) {
        int h = m - 260;
        for (int c = 0; c < 32; ++c)
            v = fmaf(W[(size_t)k * 128 + h * 32 + c], a_d[h * 32 + c], v);
    }
    BT[i] = f2bf(v);
}

// BT3: 128 rows x 128 k. rows 0..39 = W3, 40..49 = LW3, 64..67 = W3@a_s,
// 68..71 = W3@a_d, rest 0.
__device__ void packB3_body(const float* __restrict__ W3, const float* __restrict__ LW3,
                            const float* __restrict__ a_s, const float* __restrict__ a_d,
                            unsigned short* __restrict__ BT, int i) {
    if (i >= 128 * 128) return;
    int m = i >> 7, k = i & 127;
    float v = 0.f;
    if (m < 40) {
        v = W3[(size_t)k * 40 + m];
    } else if (m < 50) {
        v = LW3[(size_t)k * 10 + (m - 40)];
    } else if (m >= 64 && m < 68) {
        int h = m - 64;
        for (int c = 0; c < 10; ++c)
            v = fmaf(W3[(size_t)k * 40 + h * 10 + c], a_s[h * 10 + c], v);
    } else if (m >= 68 && m < 72) {
        int h = m - 68;
        for (int c = 0; c < 10; ++c)
            v = fmaf(W3[(size_t)k * 40 + h * 10 + c], a_d[h * 10 + c], v);
    }
    BT[i] = f2bf(v);
}

// GEMM body: 64-row block `bidx`; A frags register-resident; col-blocks looped.
__device__ void gemm_body(const unsigned short* __restrict__ A,
                          const unsigned short* __restrict__ BT,
                          unsigned short* __restrict__ C,
                          float* __restrict__ asrc, float* __restrict__ adst,
                          int nrows, int Mc, int Cstride, int permStore, int bidx) {
    const int wave = threadIdx.x >> 6;
    const int lane = threadIdx.x & 63;
    const int row0 = bidx * 64 + wave * 16;
    const int lrow = lane & 15;
    const int kgrp = lane >> 4;

    int arow = row0 + lrow;
    if (arow >= nrows) arow = nrows - 1;
    const unsigned short* Ap = A + (size_t)arow * 128 + kgrp * 8;

    short8v afrag[4];
#pragma unroll
    for (int t = 0; t < 4; ++t) afrag[t] = *(const short8v*)(Ap + t * 32);

    const int nDataBlk = Mc >> 6;
    for (int cb = 0; cb < nDataBlk; ++cb) {
        const unsigned short* Bp = BT + (size_t)(cb * 64 + lrow) * 128 + kgrp * 8;
        float4v acc[4] = {{0.f,0.f,0.f,0.f},{0.f,0.f,0.f,0.f},{0.f,0.f,0.f,0.f},{0.f,0.f,0.f,0.f}};
#pragma unroll
        for (int t = 0; t < 4; ++t) {
#pragma unroll
            for (int kk = 0; kk < 4; ++kk) {
                short8v b = *(const short8v*)(Bp + kk * 16 * 128 + t * 32);
                acc[kk] = __builtin_amdgcn_mfma_f32_16x16x32_bf16(afrag[t], b, acc[kk], 0, 0, 0);
            }
        }
#pragma unroll
        for (int r = 0; r < 4; ++r) {
            int row = row0 + kgrp * 4 + r;
            if (row >= nrows) continue;
            if (!permStore) {
                size_t base = (size_t)row * Cstride + cb * 64 + lrow;
                C[base]      = f2bf(acc[0][r]);
                C[base + 16] = f2bf(acc[1][r]);
                C[base + 32] = f2bf(acc[2][r]);
                C[base + 48] = f2bf(acc[3][r]);
            } else {
#pragma unroll
                for (int kk = 0; kk < 4; ++kk) {
                    int col = lrow + kk * 16;
                    int pos;
                    if (col < 40)      pos = (col / 5) * 8 + (col % 5);
                    else if (col < 50) pos = 64 + (col - 40);
                    else continue;
                    C[(size_t)row * 80 + pos] = f2bf(acc[kk][r]);
                }
            }
        }
    }

    // alpha block: 8 columns at BT rows Mc..Mc+7
    {
        const unsigned short* Bp = BT + (size_t)(Mc + lrow) * 128 + kgrp * 8;
        float4v acc0 = {0.f, 0.f, 0.f, 0.f};
#pragma unroll
        for (int t = 0; t < 4; ++t) {
            short8v b = *(const short8v*)(Bp + t * 32);
            acc0 = __builtin_amdgcn_mfma_f32_16x16x32_bf16(afrag[t], b, acc0, 0, 0, 0);
        }
        if (lrow < 8) {
            float* dst = (lrow < 4) ? asrc : adst;
            int hh = lrow & 3;
#pragma unroll
            for (int r = 0; r < 4; ++r) {
                int row = row0 + kgrp * 4 + r;
                if (row < nrows) dst[(size_t)row * 4 + hh] = acc0[r];
            }
        }
    }
}

// XCD-bucketed CSR fill body (bucket = bid&7 over dst ranges, FILLB blocks).
__device__ void fill_body(const int* __restrict__ ei, int E, int N,
                          const int* __restrict__ rowptr, int* __restrict__ cur,
                          int* __restrict__ adj, int bid) {
    const int bucket = bid & 7;
    const int grp    = bid >> 3;
    const int ngrp   = FILLB >> 3;
    const int npb    = (N + 7) >> 3;
    const int lo = bucket * npb;
    const int hi = (lo + npb < N) ? lo + npb : N;

    for (int i = lo + grp * 256 + (int)threadIdx.x; i < hi; i += ngrp * 256)
        adj[rowptr[i]] = i;

    const int chunkSz = 256 * FILL_U;
    const int nchunks = (E + chunkSz - 1) / chunkSz;
    const int* dstRow = ei + E;
    for (int c = grp; c < nchunks; c += ngrp) {
        int base = c * chunkSz + (int)threadIdx.x;
#pragma unroll
        for (int k = 0; k < FILL_U; ++k) {
            int e = base + k * 256;
            if (e < E) {
                int d = dstRow[e];
                if (d >= lo && d < hi) {
                    int pos = rowptr[d] + 1 + atomicAdd(&cur[d], 1);
                    adj[pos] = ei[e];
                }
            }
        }
    }
}

// ---------------- K1: castX || hist || packB1 || packB2 || packB3 ----------------
__global__ __launch_bounds__(256) void prep_fused(
    const float* __restrict__ x, unsigned short* __restrict__ xb, int nCast, int n4,
    const int* __restrict__ ei, int E, int* __restrict__ deg, int nHist,
    const float* __restrict__ W1, const float* __restrict__ l1W,
    const float* __restrict__ a1s, const float* __restrict__ a1d, unsigned short* __restrict__ BT1,
    const float* __restrict__ W2, const float* __restrict__ l2W,
    const float* __restrict__ a2s, const float* __restrict__ a2d, unsigned short* __restrict__ BT2,
    const float* __restrict__ W3, const float* __restrict__ l3W,
    const float* __restrict__ a3s, const float* __restrict__ a3d, unsigned short* __restrict__ BT3)
{
    const int nPack12 = 160;   // 320*128/256
    int b = blockIdx.x;
    if (b < nCast) {
        castX_body(x, xb, n4, b * 256 + threadIdx.x);
    } else if ((b -= nCast) < nHist) {
        hist_body(ei + E, E, deg, b * 256 + threadIdx.x);
    } else if ((b -= nHist) < nPack12) {
        packB12_body(W1, l1W, a1s, a1d, BT1, b * 256 + threadIdx.x);
    } else if ((b -= nPack12) < nPack12) {
        packB12_body(W2, l2W, a2s, a2d, BT2, b * 256 + threadIdx.x);
    } else {
        b -= nPack12;
        packB3_body(W3, l3W, a3s, a3d, BT3, b * 256 + threadIdx.x);
    }
}

// ---------------- K2: csr_fill FIRST, then gemm(L1) blocks ----------------
__global__ __launch_bounds__(256) void gemm_fill_fused(
    const unsigned short* __restrict__ A, const unsigned short* __restrict__ BT,
    unsigned short* __restrict__ C, float* __restrict__ asrc, float* __restrict__ adst,
    int nrows, int rowBlocks,
    const int* __restrict__ ei, int E, int N,
    const int* __restrict__ rowptr, int* __restrict__ cur, int* __restrict__ adj)
{
    if ((int)blockIdx.x < FILLB) {
        fill_body(ei, E, N, rowptr, cur, adj, blockIdx.x);
    } else {
        int gb = blockIdx.x - FILLB;
        if (gb < rowBlocks)
            gemm_body(A, BT, C, asrc, adst, nrows, 256, 256, 0, gb);
    }
}

// ---------------- standalone GEMM (layers 2,3) ----------------
__global__ __launch_bounds__(256) void mfma_gemm(const unsigned short* __restrict__ A,
                                                 const unsigned short* __restrict__ BT,
                                                 unsigned short* __restrict__ C,
                                                 float* __restrict__ asrc,
                                                 float* __restrict__ adst,
                                                 int nrows, int Mc, int Cstride,
                                                 int permStore) {
    gemm_body(A, BT, C, asrc, adst, nrows, Mc, Cstride, permStore, blockIdx.x);
}

// ---------------- scan kernels ----------------
__global__ void scan_block(const int* __restrict__ in, int* __restrict__ out,
                           int* __restrict__ bsum, int n) {
    __shared__ int tmp[256];
    int i = blockIdx.x * 256 + threadIdx.x;
    int v = (i < n) ? in[i] + 1 : 0;   // +1: self-loop slot
    tmp[threadIdx.x] = v;
    __syncthreads();
    for (int d = 1; d < 256; d <<= 1) {
        int t = (threadIdx.x >= d) ? tmp[threadIdx.x - d] : 0;
        __syncthreads();
        tmp[threadIdx.x] += t;
        __syncthreads();
    }
    if (i < n) out[i] = tmp[threadIdx.x] - v;
    if (threadIdx.x == 255) bsum[blockIdx.x] = tmp[255];
}

__global__ void scan_bsum(int* bsum, int nb) {
    __shared__ int tmp[256];
    int v = (threadIdx.x < nb) ? bsum[threadIdx.x] : 0;
    tmp[threadIdx.x] = v;
    __syncthreads();
    for (int d = 1; d < 256; d <<= 1) {
        int t = (threadIdx.x >= d) ? tmp[threadIdx.x - d] : 0;
        __syncthreads();
        tmp[threadIdx.x] += t;
        __syncthreads();
    }
    if (threadIdx.x < nb) bsum[threadIdx.x] = tmp[threadIdx.x] - v;
}

__global__ void scan_add(int* out, const int* __restrict__ bsum, int n) {
    int i = blockIdx.x * 256 + threadIdx.x;
    if (i < n) out[i] += bsum[blockIdx.x];
}

// ---------------- fused gather (HC=128): one wave per dst node ----------------
// 4 edge slots x 16 lanes x 8 channels; quad-unrolled.
__global__ __launch_bounds__(256) void gat_gather128(
    const int* __restrict__ rowptr, const int* __restrict__ adj, int ET,
    const float* __restrict__ asrc, const float* __restrict__ adst,
    const unsigned short* __restrict__ Hb,
    const float* __restrict__ bias, const float* __restrict__ lbias,
    unsigned short* __restrict__ xout, int n)
{
    int node = (blockIdx.x * 256 + threadIdx.x) >> 6;
    int lane = threadIdx.x & 63;
    if (node >= n) return;
    int beg = rowptr[node];
    int end = (node + 1 < n) ? rowptr[node + 1] : ET;

    int ep = lane >> 4;
    int q  = lane & 15;
    int c0 = q * 8;
    int h  = q >> 2;
    float adh = adst[(size_t)node * 4 + h];

    float accp = 0.f;
    float a[8];
#pragma unroll
    for (int k = 0; k < 8; ++k) a[k] = 0.f;

    int j = beg + ep;
    while (j < end) {
        int j1 = j + 4, j2 = j + 8, j3 = j + 12;
        bool v1 = j1 < end, v2 = j2 < end, v3 = j3 < end;
        int s0 = adj[j];
        int s1 = v1 ? adj[j1] : s0;
        int s2 = v2 ? adj[j2] : s0;
        int s3 = v3 ? adj[j3] : s0;
        float av0 = asrc[(size_t)s0 * 4 + h];
        float av1 = asrc[(size_t)s1 * 4 + h];
        float av2 = asrc[(size_t)s2 * 4 + h];
        float av3 = asrc[(size_t)s3 * 4 + h];
        short8v hv0 = *(const short8v*)&Hb[(size_t)s0 * 256 + c0];
        short8v hv1 = *(const short8v*)&Hb[(size_t)s1 * 256 + c0];
        short8v hv2 = *(const short8v*)&Hb[(size_t)s2 * 256 + c0];
        short8v hv3 = *(const short8v*)&Hb[(size_t)s3 * 256 + c0];
        float p0 = __expf(lrelu(av0 + adh));
        float p1 = v1 ? __expf(lrelu(av1 + adh)) : 0.f;
        float p2 = v2 ? __expf(lrelu(av2 + adh)) : 0.f;
        float p3 = v3 ? __expf(lrelu(av3 + adh)) : 0.f;
        accp += (p0 + p1) + (p2 + p3);
#pragma unroll
        for (int k = 0; k < 8; ++k) {
            float t0 = fmaf(p0, bf2f((unsigned short)hv0[k]), a[k]);
            float t1 = fmaf(p1, bf2f((unsigned short)hv1[k]), t0);
            float t2 = fmaf(p2, bf2f((unsigned short)hv2[k]), t1);
            a[k] = fmaf(p3, bf2f((unsigned short)hv3[k]), t2);
        }
        j += 16;
    }
#pragma unroll
    for (int off = 16; off <= 32; off <<= 1) {
        accp += __shfl_xor(accp, off);
#pragma unroll
        for (int k = 0; k < 8; ++k) a[k] += __shfl_xor(a[k], off);
    }

    if (ep == 0) {
        float inv = 1.f / (accp + 1e-16f);
        short8v lv = *(const short8v*)&Hb[(size_t)node * 256 + 128 + c0];
        unsigned short w[8];
#pragma unroll
        for (int k = 0; k < 8; ++k) {
            float v = a[k] * inv + bias[c0 + k] + bf2f((unsigned short)lv[k]) + lbias[c0 + k];
            v = v > 0.f ? v : __expf(v) - 1.f;
            w[k] = f2bf(v);
        }
        *(short8v*)&xout[(size_t)node * 128 + c0] = *(short8v*)w;
    }
}

// ---------------- fused gather layer 3 (C=10, mean over heads) ----------------
// 8 edge slots x 8 lanes x 5 channels; quad-unrolled. Hb3 stride 80 padded.
__global__ __launch_bounds__(256) void gat_gather40(
    const int* __restrict__ rowptr, const int* __restrict__ adj, int ET,
    const float* __restrict__ asrc, const float* __restrict__ adst,
    const unsigned short* __restrict__ Hb3,
    const float* __restrict__ bias, const float* __restrict__ lbias,
    float* __restrict__ out, int n)
{
    int node = (blockIdx.x * 256 + threadIdx.x) >> 6;
    int lane = threadIdx.x & 63;
    if (node >= n) return;
    int beg = rowptr[node];
    int end = (node + 1 < n) ? rowptr[node + 1] : ET;

    int slot = lane >> 3;
    int sub  = lane & 7;
    int h    = sub >> 1;
    float adh = adst[(size_t)node * 4 + h];

    float accp = 0.f;
    float a[5];
#pragma unroll
    for (int k = 0; k < 5; ++k) a[k] = 0.f;

    int j = beg + slot;
    while (j < end) {
        int j1 = j + 8, j2 = j + 16, j3 = j + 24;
        bool v1 = j1 < end, v2 = j2 < end, v3 = j3 < end;
        int s0 = adj[j];
        int s1 = v1 ? adj[j1] : s0;
        int s2 = v2 ? adj[j2] : s0;
        int s3 = v3 ? adj[j3] : s0;
        float av0 = asrc[(size_t)s0 * 4 + h];
        float av1 = asrc[(size_t)s1 * 4 + h];
        float av2 = asrc[(size_t)s2 * 4 + h];
        float av3 = asrc[(size_t)s3 * 4 + h];
        short8v hv0 = *(const short8v*)&Hb3[(size_t)s0 * 80 + sub * 8];
        short8v hv1 = *(const short8v*)&Hb3[(size_t)s1 * 80 + sub * 8];
        short8v hv2 = *(const short8v*)&Hb3[(size_t)s2 * 80 + sub * 8];
        short8v hv3 = *(const short8v*)&Hb3[(size_t)s3 * 80 + sub * 8];
        float p0 = __expf(lrelu(av0 + adh));
        float p1 = v1 ? __expf(lrelu(av1 + adh)) : 0.f;
        float p2 = v2 ? __expf(lrelu(av2 + adh)) : 0.f;
        float p3 = v3 ? __expf(lrelu(av3 + adh)) : 0.f;
        accp += (p0 + p1) + (p2 + p3);
#pragma unroll
        for (int k = 0; k < 5; ++k) {
            float t0 = fmaf(p0, bf2f((unsigned short)hv0[k]), a[k]);
            float t1 = fmaf(p1, bf2f((unsigned short)hv1[k]), t0);
            float t2 = fmaf(p2, bf2f((unsigned short)hv2[k]), t1);
            a[k] = fmaf(p3, bf2f((unsigned short)hv3[k]), t2);
        }
        j += 32;
    }
#pragma unroll
    for (int off = 8; off <= 32; off <<= 1) {
        accp += __shfl_xor(accp, off);
#pragma unroll
        for (int k = 0; k < 5; ++k) a[k] += __shfl_xor(a[k], off);
    }
    float inv = 0.25f / (accp + 1e-16f);
#pragma unroll
    for (int k = 0; k < 5; ++k) a[k] *= inv;
#pragma unroll
    for (int off = 2; off <= 4; off <<= 1) {
#pragma unroll
        for (int k = 0; k < 5; ++k) a[k] += __shfl_xor(a[k], off);
    }

    if (lane < 2) {
        int cc0 = sub * 5;
#pragma unroll
        for (int k = 0; k < 5; ++k) {
            float lin = bf2f(Hb3[(size_t)node * 80 + 64 + cc0 + k]);
            out[(size_t)node * 10 + cc0 + k] = a[k] + bias[cc0 + k] + lin + lbias[cc0 + k];
        }
    }
}

extern "C" void kernel_launch(void* const* d_in, const int* in_sizes, int n_in,
                              void* d_out, int out_size, void* d_ws, size_t ws_size,
                              hipStream_t stream) {
    const float* x   = (const float*)d_in[0];
    const int*   ei  = (const int*)d_in[1];
    const float* W1  = (const float*)d_in[2];
    const float* a1s = (const float*)d_in[3];
    const float* a1d = (const float*)d_in[4];
    const float* b1  = (const float*)d_in[5];
    const float* l1W = (const float*)d_in[6];
    const float* l1b = (const float*)d_in[7];
    const float* W2  = (const float*)d_in[8];
    const float* a2s = (const float*)d_in[9];
    const float* a2d = (const float*)d_in[10];
    const float* b2  = (const float*)d_in[11];
    const float* l2W = (const float*)d_in[12];
    const float* l2b = (const float*)d_in[13];
    const float* W3  = (const float*)d_in[14];
    const float* a3s = (const float*)d_in[15];
    const float* a3d = (const float*)d_in[16];
    const float* b3  = (const float*)d_in[17];
    const float* l3W = (const float*)d_in[18];
    const float* l3b = (const float*)d_in[19];

    const int N  = in_sizes[0] / 128;
    const int E  = in_sizes[1] / 2;
    const int ET = E + N;

    unsigned short* Xb  = (unsigned short*)d_ws;          // N*128 bf16
    unsigned short* Hb  = Xb + (size_t)N * 128;           // N*256 bf16 (layer3: N*80)
    unsigned short* BT1 = Hb + (size_t)N * 256;           // 320*128 bf16
    unsigned short* BT2 = BT1 + 320 * 128;                // 320*128 bf16
    unsigned short* BT3 = BT2 + 320 * 128;                // 128*128 bf16
    float* asrc = (float*)(BT3 + 128 * 128);              // N*4
    float* adst = asrc + (size_t)N * 4;                   // N*4
    int* deg    = (int*)(adst + (size_t)N * 4);           // N
    int* cur    = deg + N;                                // N (adjacent for one memset)
    int* rowptr = cur + N;                                // N
    int* bsum   = rowptr + N;                             // 256
    int* adj    = bsum + 256;                             // ET ints

    const int nScanBlocks = (N + 255) / 256;
    const int waveBlocks  = (N * 64 + 255) / 256;
    const int rowBlocks   = (N + 63) / 64;
    const int nCast = (N * 32 + 255) / 256;
    const int nHist = (E / 4 + 256) / 256;
    const int prepBlocks = nCast + nHist + 160 + 160 + 64;

    // ---------- prep: memset; K1 = castX || hist || packB x3 ----------
    hipMemsetAsync(deg, 0, (size_t)N * 2 * 4, stream);    // deg + cur
    prep_fused<<<prepBlocks, 256, 0, stream>>>(
        x, Xb, nCast, N * 32, ei, E, deg, nHist,
        W1, l1W, a1s, a1d, BT1, W2, l2W, a2s, a2d, BT2, W3, l3W, a3s, a3d, BT3);
    scan_block<<<nScanBlocks, 256, 0, stream>>>(deg, rowptr, bsum, N);
    scan_bsum<<<1, 256, 0, stream>>>(bsum, nScanBlocks);
    scan_add<<<nScanBlocks, 256, 0, stream>>>(rowptr, bsum, N);

    // ---------- layer 1 (csr_fill first, gemm behind) ----------
    gemm_fill_fused<<<FILLB + rowBlocks, 256, 0, stream>>>(
        Xb, BT1, Hb, asrc, adst, N, rowBlocks, ei, E, N, rowptr, cur, adj);
    gat_gather128<<<waveBlocks, 256, 0, stream>>>(rowptr, adj, ET, asrc, adst, Hb, b1, l1b, Xb, N);

    // ---------- layer 2 ----------
    mfma_gemm<<<rowBlocks, 256, 0, stream>>>(Xb, BT2, Hb, asrc, adst, N, 256, 256, 0);
    gat_gather128<<<waveBlocks, 256, 0, stream>>>(rowptr, adj, ET, asrc, adst, Hb, b2, l2b, Xb, N);

    // ---------- layer 3 ----------
    mfma_gemm<<<rowBlocks, 256, 0, stream>>>(Xb, BT3, Hb, asrc, adst, N, 64, 80, 1);
    gat_gather40<<<waveBlocks, 256, 0, stream>>>(rowptr, adj, ET, asrc, adst, Hb, b3, l3b, (float*)d_out, N);
}

// Round 15
// 293.423 us; speedup vs baseline: 1.0251x; 1.0251x over previous
//
#include <hip/hip_runtime.h>
#include <math.h>

// 3-layer GAT. Round 15: overlap experiments abandoned (R12-R14 all lost to
// plain serial kernels). Structure: fused prep -> scans -> standalone
// csr_fill (int4-vectorized dst/src reads) -> standalone GEMMs -> gathers.
// Quad-unrolled gather128/gather40, col-block-looped GEMM, fused prep kept.

#define HEADS 4
#define FILLB 4096

typedef __attribute__((ext_vector_type(8))) short short8v;   // 8 bf16
typedef __attribute__((ext_vector_type(4))) float float4v;   // 4 fp32 acc

__device__ __forceinline__ float lrelu(float v) { return v > 0.f ? v : 0.2f * v; }

__device__ __forceinline__ unsigned short f2bf(float f) {
    unsigned u = __float_as_uint(f);
    unsigned r = u + 0x7FFFu + ((u >> 16) & 1u);   // RNE
    return (unsigned short)(r >> 16);
}
__device__ __forceinline__ float bf2f(unsigned short u) {
    return __uint_as_float(((unsigned)u) << 16);
}

// ---------------- device bodies ----------------
__device__ void castX_body(const float* __restrict__ x, unsigned short* __restrict__ xb,
                           int n4, int i) {
    if (i >= n4) return;
    float4 v = *(const float4*)&x[(size_t)i * 4];
    ushort4 o;
    o.x = f2bf(v.x); o.y = f2bf(v.y); o.z = f2bf(v.z); o.w = f2bf(v.w);
    *(ushort4*)&xb[(size_t)i * 4] = o;
}

__device__ void hist_body(const int* __restrict__ dst, int E, int* __restrict__ deg, int t) {
    int e = t * 4;
    if (e + 3 < E) {
        int4 d = *(const int4*)&dst[e];
        atomicAdd(&deg[d.x], 1);
        atomicAdd(&deg[d.y], 1);
        atomicAdd(&deg[d.z], 1);
        atomicAdd(&deg[d.w], 1);
    } else {
        for (; e < E; ++e) atomicAdd(&deg[dst[e]], 1);
    }
}

// BT12: (256+64) rows x 128 k. rows 0..127 = W, 128..255 = LW, 256..259 = W@a_s,
// 260..263 = W@a_d, rest 0.
__device__ void packB12_body(const float* __restrict__ W, const float* __restrict__ LW,
                             const float* __restrict__ a_s, const float* __restrict__ a_d,
                             unsigned short* __restrict__ BT, int i) {
    if (i >= 320 * 128) return;
    int m = i >> 7, k = i & 127;
    float v = 0.f;
    if (m < 128) {
        v = W[(size_t)k * 128 + m];
    } else if (m < 256) {
        v = LW[(size_t)k * 128 + (m - 128)];
    } else if (m < 260) {
        int h = m - 256;
        for (int c = 0; c < 32; ++c)
            v = fmaf(W[(size_t)k * 128 + h * 32 + c], a_s[h * 32 + c], v);
    } else if (m < 264) {
        int h = m - 260;
        for (int c = 0; c < 32; ++c)
            v = fmaf(W[(size_t)k * 128 + h * 32 + c], a_d[h * 32 + c], v);
    }
    BT[i] = f2bf(v);
}

// BT3: 128 rows x 128 k. rows 0..39 = W3, 40..49 = LW3, 64..67 = W3@a_s,
// 68..71 = W3@a_d, rest 0.
__device__ void packB3_body(const float* __restrict__ W3, const float* __restrict__ LW3,
                            const float* __restrict__ a_s, const float* __restrict__ a_d,
                            unsigned short* __restrict__ BT, int i) {
    if (i >= 128 * 128) return;
    int m = i >> 7, k = i & 127;
    float v = 0.f;
    if (m < 40) {
        v = W3[(size_t)k * 40 + m];
    } else if (m < 50) {
        v = LW3[(size_t)k * 10 + (m - 40)];
    } else if (m >= 64 && m < 68) {
        int h = m - 64;
        for (int c = 0; c < 10; ++c)
            v = fmaf(W3[(size_t)k * 40 + h * 10 + c], a_s[h * 10 + c], v);
    } else if (m >= 68 && m < 72) {
        int h = m - 68;
        for (int c = 0; c < 10; ++c)
            v = fmaf(W3[(size_t)k * 40 + h * 10 + c], a_d[h * 10 + c], v);
    }
    BT[i] = f2bf(v);
}

// ---------------- K1: castX || hist || packB1 || packB2 || packB3 ----------------
__global__ __launch_bounds__(256) void prep_fused(
    const float* __restrict__ x, unsigned short* __restrict__ xb, int nCast, int n4,
    const int* __restrict__ ei, int E, int* __restrict__ deg, int nHist,
    const float* __restrict__ W1, const float* __restrict__ l1W,
    const float* __restrict__ a1s, const float* __restrict__ a1d, unsigned short* __restrict__ BT1,
    const float* __restrict__ W2, const float* __restrict__ l2W,
    const float* __restrict__ a2s, const float* __restrict__ a2d, unsigned short* __restrict__ BT2,
    const float* __restrict__ W3, const float* __restrict__ l3W,
    const float* __restrict__ a3s, const float* __restrict__ a3d, unsigned short* __restrict__ BT3)
{
    const int nPack12 = 160;   // 320*128/256
    int b = blockIdx.x;
    if (b < nCast) {
        castX_body(x, xb, n4, b * 256 + threadIdx.x);
    } else if ((b -= nCast) < nHist) {
        hist_body(ei + E, E, deg, b * 256 + threadIdx.x);
    } else if ((b -= nHist) < nPack12) {
        packB12_body(W1, l1W, a1s, a1d, BT1, b * 256 + threadIdx.x);
    } else if ((b -= nPack12) < nPack12) {
        packB12_body(W2, l2W, a2s, a2d, BT2, b * 256 + threadIdx.x);
    } else {
        b -= nPack12;
        packB3_body(W3, l3W, a3s, a3d, BT3, b * 256 + threadIdx.x);
    }
}

// ---------------- XCD-bucketed CSR fill (int4 dst/src reads) ----------------
__global__ __launch_bounds__(256) void csr_fill_bucket(
    const int* __restrict__ ei, int E, int N,
    const int* __restrict__ rowptr, int* __restrict__ cur,
    int* __restrict__ adj)
{
    const int bucket = blockIdx.x & 7;
    const int grp    = blockIdx.x >> 3;
    const int ngrp   = FILLB >> 3;
    const int npb    = (N + 7) >> 3;
    const int lo = bucket * npb;
    const int hi = (lo + npb < N) ? lo + npb : N;

    // self-loops for this bucket's nodes (first slot of each segment)
    for (int i = lo + grp * 256 + (int)threadIdx.x; i < hi; i += ngrp * 256)
        adj[rowptr[i]] = i;

    // edges: 1024-edge chunks; each thread loads 4 contiguous (dst,src) int4s
    const int chunkSz = 1024;
    const int nchunks = (E + chunkSz - 1) / chunkSz;
    const int* dstRow = ei + E;
    for (int c = grp; c < nchunks; c += ngrp) {
        int base = c * chunkSz + (int)threadIdx.x * 4;
        if (base + 3 < E) {
            int4 d4 = *(const int4*)&dstRow[base];
            int4 s4 = *(const int4*)&ei[base];
            int dd[4] = {d4.x, d4.y, d4.z, d4.w};
            int ss[4] = {s4.x, s4.y, s4.z, s4.w};
#pragma unroll
            for (int k = 0; k < 4; ++k) {
                int d = dd[k];
                if (d >= lo && d < hi) {
                    int pos = rowptr[d] + 1 + atomicAdd(&cur[d], 1);
                    adj[pos] = ss[k];
                }
            }
        } else {
            for (int e = base; e < E; ++e) {
                int d = dstRow[e];
                if (d >= lo && d < hi) {
                    int pos = rowptr[d] + 1 + atomicAdd(&cur[d], 1);
                    adj[pos] = ei[e];
                }
            }
        }
    }
}

// ---------------- MFMA GEMM, col-blocks looped in-block ----------------
__global__ __launch_bounds__(256) void mfma_gemm(const unsigned short* __restrict__ A,
                                                 const unsigned short* __restrict__ BT,
                                                 unsigned short* __restrict__ C,
                                                 float* __restrict__ asrc,
                                                 float* __restrict__ adst,
                                                 int nrows, int Mc, int Cstride,
                                                 int permStore) {
    const int wave = threadIdx.x >> 6;
    const int lane = threadIdx.x & 63;
    const int row0 = blockIdx.x * 64 + wave * 16;
    const int lrow = lane & 15;
    const int kgrp = lane >> 4;

    int arow = row0 + lrow;
    if (arow >= nrows) arow = nrows - 1;
    const unsigned short* Ap = A + (size_t)arow * 128 + kgrp * 8;

    short8v afrag[4];
#pragma unroll
    for (int t = 0; t < 4; ++t) afrag[t] = *(const short8v*)(Ap + t * 32);

    const int nDataBlk = Mc >> 6;
    for (int cb = 0; cb < nDataBlk; ++cb) {
        const unsigned short* Bp = BT + (size_t)(cb * 64 + lrow) * 128 + kgrp * 8;
        float4v acc[4] = {{0.f,0.f,0.f,0.f},{0.f,0.f,0.f,0.f},{0.f,0.f,0.f,0.f},{0.f,0.f,0.f,0.f}};
#pragma unroll
        for (int t = 0; t < 4; ++t) {
#pragma unroll
            for (int kk = 0; kk < 4; ++kk) {
                short8v b = *(const short8v*)(Bp + kk * 16 * 128 + t * 32);
                acc[kk] = __builtin_amdgcn_mfma_f32_16x16x32_bf16(afrag[t], b, acc[kk], 0, 0, 0);
            }
        }
#pragma unroll
        for (int r = 0; r < 4; ++r) {
            int row = row0 + kgrp * 4 + r;
            if (row >= nrows) continue;
            if (!permStore) {
                size_t base = (size_t)row * Cstride + cb * 64 + lrow;
                C[base]      = f2bf(acc[0][r]);
                C[base + 16] = f2bf(acc[1][r]);
                C[base + 32] = f2bf(acc[2][r]);
                C[base + 48] = f2bf(acc[3][r]);
            } else {
#pragma unroll
                for (int kk = 0; kk < 4; ++kk) {
                    int col = lrow + kk * 16;
                    int pos;
                    if (col < 40)      pos = (col / 5) * 8 + (col % 5);
                    else if (col < 50) pos = 64 + (col - 40);
                    else continue;
                    C[(size_t)row * 80 + pos] = f2bf(acc[kk][r]);
                }
            }
        }
    }

    // alpha block: 8 columns at BT rows Mc..Mc+7
    {
        const unsigned short* Bp = BT + (size_t)(Mc + lrow) * 128 + kgrp * 8;
        float4v acc0 = {0.f, 0.f, 0.f, 0.f};
#pragma unroll
        for (int t = 0; t < 4; ++t) {
            short8v b = *(const short8v*)(Bp + t * 32);
            acc0 = __builtin_amdgcn_mfma_f32_16x16x32_bf16(afrag[t], b, acc0, 0, 0, 0);
        }
        if (lrow < 8) {
            float* dst = (lrow < 4) ? asrc : adst;
            int hh = lrow & 3;
#pragma unroll
            for (int r = 0; r < 4; ++r) {
                int row = row0 + kgrp * 4 + r;
                if (row < nrows) dst[(size_t)row * 4 + hh] = acc0[r];
            }
        }
    }
}

// ---------------- scan kernels ----------------
__global__ void scan_block(const int* __restrict__ in, int* __restrict__ out,
                           int* __restrict__ bsum, int n) {
    __shared__ int tmp[256];
    int i = blockIdx.x * 256 + threadIdx.x;
    int v = (i < n) ? in[i] + 1 : 0;   // +1: self-loop slot
    tmp[threadIdx.x] = v;
    __syncthreads();
    for (int d = 1; d < 256; d <<= 1) {
        int t = (threadIdx.x >= d) ? tmp[threadIdx.x - d] : 0;
        __syncthreads();
        tmp[threadIdx.x] += t;
        __syncthreads();
    }
    if (i < n) out[i] = tmp[threadIdx.x] - v;
    if (threadIdx.x == 255) bsum[blockIdx.x] = tmp[255];
}

__global__ void scan_bsum(int* bsum, int nb) {
    __shared__ int tmp[256];
    int v = (threadIdx.x < nb) ? bsum[threadIdx.x] : 0;
    tmp[threadIdx.x] = v;
    __syncthreads();
    for (int d = 1; d < 256; d <<= 1) {
        int t = (threadIdx.x >= d) ? tmp[threadIdx.x - d] : 0;
        __syncthreads();
        tmp[threadIdx.x] += t;
        __syncthreads();
    }
    if (threadIdx.x < nb) bsum[threadIdx.x] = tmp[threadIdx.x] - v;
}

__global__ void scan_add(int* out, const int* __restrict__ bsum, int n) {
    int i = blockIdx.x * 256 + threadIdx.x;
    if (i < n) out[i] += bsum[blockIdx.x];
}

// ---------------- fused gather (HC=128): one wave per dst node ----------------
// 4 edge slots x 16 lanes x 8 channels; quad-unrolled.
__global__ __launch_bounds__(256) void gat_gather128(
    const int* __restrict__ rowptr, const int* __restrict__ adj, int ET,
    const float* __restrict__ asrc, const float* __restrict__ adst,
    const unsigned short* __restrict__ Hb,
    const float* __restrict__ bias, const float* __restrict__ lbias,
    unsigned short* __restrict__ xout, int n)
{
    int node = (blockIdx.x * 256 + threadIdx.x) >> 6;
    int lane = threadIdx.x & 63;
    if (node >= n) return;
    int beg = rowptr[node];
    int end = (node + 1 < n) ? rowptr[node + 1] : ET;

    int ep = lane >> 4;
    int q  = lane & 15;
    int c0 = q * 8;
    int h  = q >> 2;
    float adh = adst[(size_t)node * 4 + h];

    float accp = 0.f;
    float a[8];
#pragma unroll
    for (int k = 0; k < 8; ++k) a[k] = 0.f;

    int j = beg + ep;
    while (j < end) {
        int j1 = j + 4, j2 = j + 8, j3 = j + 12;
        bool v1 = j1 < end, v2 = j2 < end, v3 = j3 < end;
        int s0 = adj[j];
        int s1 = v1 ? adj[j1] : s0;
        int s2 = v2 ? adj[j2] : s0;
        int s3 = v3 ? adj[j3] : s0;
        float av0 = asrc[(size_t)s0 * 4 + h];
        float av1 = asrc[(size_t)s1 * 4 + h];
        float av2 = asrc[(size_t)s2 * 4 + h];
        float av3 = asrc[(size_t)s3 * 4 + h];
        short8v hv0 = *(const short8v*)&Hb[(size_t)s0 * 256 + c0];
        short8v hv1 = *(const short8v*)&Hb[(size_t)s1 * 256 + c0];
        short8v hv2 = *(const short8v*)&Hb[(size_t)s2 * 256 + c0];
        short8v hv3 = *(const short8v*)&Hb[(size_t)s3 * 256 + c0];
        float p0 = __expf(lrelu(av0 + adh));
        float p1 = v1 ? __expf(lrelu(av1 + adh)) : 0.f;
        float p2 = v2 ? __expf(lrelu(av2 + adh)) : 0.f;
        float p3 = v3 ? __expf(lrelu(av3 + adh)) : 0.f;
        accp += (p0 + p1) + (p2 + p3);
#pragma unroll
        for (int k = 0; k < 8; ++k) {
            float t0 = fmaf(p0, bf2f((unsigned short)hv0[k]), a[k]);
            float t1 = fmaf(p1, bf2f((unsigned short)hv1[k]), t0);
            float t2 = fmaf(p2, bf2f((unsigned short)hv2[k]), t1);
            a[k] = fmaf(p3, bf2f((unsigned short)hv3[k]), t2);
        }
        j += 16;
    }
#pragma unroll
    for (int off = 16; off <= 32; off <<= 1) {
        accp += __shfl_xor(accp, off);
#pragma unroll
        for (int k = 0; k < 8; ++k) a[k] += __shfl_xor(a[k], off);
    }

    if (ep == 0) {
        float inv = 1.f / (accp + 1e-16f);
        short8v lv = *(const short8v*)&Hb[(size_t)node * 256 + 128 + c0];
        unsigned short w[8];
#pragma unroll
        for (int k = 0; k < 8; ++k) {
            float v = a[k] * inv + bias[c0 + k] + bf2f((unsigned short)lv[k]) + lbias[c0 + k];
            v = v > 0.f ? v : __expf(v) - 1.f;
            w[k] = f2bf(v);
        }
        *(short8v*)&xout[(size_t)node * 128 + c0] = *(short8v*)w;
    }
}

// ---------------- fused gather layer 3 (C=10, mean over heads) ----------------
// 8 edge slots x 8 lanes x 5 channels; quad-unrolled. Hb3 stride 80 padded.
__global__ __launch_bounds__(256) void gat_gather40(
    const int* __restrict__ rowptr, const int* __restrict__ adj, int ET,
    const float* __restrict__ asrc, const float* __restrict__ adst,
    const unsigned short* __restrict__ Hb3,
    const float* __restrict__ bias, const float* __restrict__ lbias,
    float* __restrict__ out, int n)
{
    int node = (blockIdx.x * 256 + threadIdx.x) >> 6;
    int lane = threadIdx.x & 63;
    if (node >= n) return;
    int beg = rowptr[node];
    int end = (node + 1 < n) ? rowptr[node + 1] : ET;

    int slot = lane >> 3;
    int sub  = lane & 7;
    int h    = sub >> 1;
    float adh = adst[(size_t)node * 4 + h];

    float accp = 0.f;
    float a[5];
#pragma unroll
    for (int k = 0; k < 5; ++k) a[k] = 0.f;

    int j = beg + slot;
    while (j < end) {
        int j1 = j + 8, j2 = j + 16, j3 = j + 24;
        bool v1 = j1 < end, v2 = j2 < end, v3 = j3 < end;
        int s0 = adj[j];
        int s1 = v1 ? adj[j1] : s0;
        int s2 = v2 ? adj[j2] : s0;
        int s3 = v3 ? adj[j3] : s0;
        float av0 = asrc[(size_t)s0 * 4 + h];
        float av1 = asrc[(size_t)s1 * 4 + h];
        float av2 = asrc[(size_t)s2 * 4 + h];
        float av3 = asrc[(size_t)s3 * 4 + h];
        short8v hv0 = *(const short8v*)&Hb3[(size_t)s0 * 80 + sub * 8];
        short8v hv1 = *(const short8v*)&Hb3[(size_t)s1 * 80 + sub * 8];
        short8v hv2 = *(const short8v*)&Hb3[(size_t)s2 * 80 + sub * 8];
        short8v hv3 = *(const short8v*)&Hb3[(size_t)s3 * 80 + sub * 8];
        float p0 = __expf(lrelu(av0 + adh));
        float p1 = v1 ? __expf(lrelu(av1 + adh)) : 0.f;
        float p2 = v2 ? __expf(lrelu(av2 + adh)) : 0.f;
        float p3 = v3 ? __expf(lrelu(av3 + adh)) : 0.f;
        accp += (p0 + p1) + (p2 + p3);
#pragma unroll
        for (int k = 0; k < 5; ++k) {
            float t0 = fmaf(p0, bf2f((unsigned short)hv0[k]), a[k]);
            float t1 = fmaf(p1, bf2f((unsigned short)hv1[k]), t0);
            float t2 = fmaf(p2, bf2f((unsigned short)hv2[k]), t1);
            a[k] = fmaf(p3, bf2f((unsigned short)hv3[k]), t2);
        }
        j += 32;
    }
#pragma unroll
    for (int off = 8; off <= 32; off <<= 1) {
        accp += __shfl_xor(accp, off);
#pragma unroll
        for (int k = 0; k < 5; ++k) a[k] += __shfl_xor(a[k], off);
    }
    float inv = 0.25f / (accp + 1e-16f);
#pragma unroll
    for (int k = 0; k < 5; ++k) a[k] *= inv;
#pragma unroll
    for (int off = 2; off <= 4; off <<= 1) {
#pragma unroll
        for (int k = 0; k < 5; ++k) a[k] += __shfl_xor(a[k], off);
    }

    if (lane < 2) {
        int cc0 = sub * 5;
#pragma unroll
        for (int k = 0; k < 5; ++k) {
            float lin = bf2f(Hb3[(size_t)node * 80 + 64 + cc0 + k]);
            out[(size_t)node * 10 + cc0 + k] = a[k] + bias[cc0 + k] + lin + lbias[cc0 + k];
        }
    }
}

extern "C" void kernel_launch(void* const* d_in, const int* in_sizes, int n_in,
                              void* d_out, int out_size, void* d_ws, size_t ws_size,
                              hipStream_t stream) {
    const float* x   = (const float*)d_in[0];
    const int*   ei  = (const int*)d_in[1];
    const float* W1  = (const float*)d_in[2];
    const float* a1s = (const float*)d_in[3];
    const float* a1d = (const float*)d_in[4];
    const float* b1  = (const float*)d_in[5];
    const float* l1W = (const float*)d_in[6];
    const float* l1b = (const float*)d_in[7];
    const float* W2  = (const float*)d_in[8];
    const float* a2s = (const float*)d_in[9];
    const float* a2d = (const float*)d_in[10];
    const float* b2  = (const float*)d_in[11];
    const float* l2W = (const float*)d_in[12];
    const float* l2b = (const float*)d_in[13];
    const float* W3  = (const float*)d_in[14];
    const float* a3s = (const float*)d_in[15];
    const float* a3d = (const float*)d_in[16];
    const float* b3  = (const float*)d_in[17];
    const float* l3W = (const float*)d_in[18];
    const float* l3b = (const float*)d_in[19];

    const int N  = in_sizes[0] / 128;
    const int E  = in_sizes[1] / 2;
    const int ET = E + N;

    unsigned short* Xb  = (unsigned short*)d_ws;          // N*128 bf16
    unsigned short* Hb  = Xb + (size_t)N * 128;           // N*256 bf16 (layer3: N*80)
    unsigned short* BT1 = Hb + (size_t)N * 256;           // 320*128 bf16
    unsigned short* BT2 = BT1 + 320 * 128;                // 320*128 bf16
    unsigned short* BT3 = BT2 + 320 * 128;                // 128*128 bf16
    float* asrc = (float*)(BT3 + 128 * 128);              // N*4
    float* adst = asrc + (size_t)N * 4;                   // N*4
    int* deg    = (int*)(adst + (size_t)N * 4);           // N
    int* cur    = deg + N;                                // N (adjacent for one memset)
    int* rowptr = cur + N;                                // N
    int* bsum   = rowptr + N;                             // 256
    int* adj    = bsum + 256;                             // ET ints

    const int nScanBlocks = (N + 255) / 256;
    const int waveBlocks  = (N * 64 + 255) / 256;
    const int rowBlocks   = (N + 63) / 64;
    const int nCast = (N * 32 + 255) / 256;
    const int nHist = (E / 4 + 256) / 256;
    const int prepBlocks = nCast + nHist + 160 + 160 + 64;

    // ---------- prep: memset; K1 = castX || hist || packB x3; scans ----------
    hipMemsetAsync(deg, 0, (size_t)N * 2 * 4, stream);    // deg + cur
    prep_fused<<<prepBlocks, 256, 0, stream>>>(
        x, Xb, nCast, N * 32, ei, E, deg, nHist,
        W1, l1W, a1s, a1d, BT1, W2, l2W, a2s, a2d, BT2, W3, l3W, a3s, a3d, BT3);
    scan_block<<<nScanBlocks, 256, 0, stream>>>(deg, rowptr, bsum, N);
    scan_bsum<<<1, 256, 0, stream>>>(bsum, nScanBlocks);
    scan_add<<<nScanBlocks, 256, 0, stream>>>(rowptr, bsum, N);
    csr_fill_bucket<<<FILLB, 256, 0, stream>>>(ei, E, N, rowptr, cur, adj);

    // ---------- layer 1 ----------
    mfma_gemm<<<rowBlocks, 256, 0, stream>>>(Xb, BT1, Hb, asrc, adst, N, 256, 256, 0);
    gat_gather128<<<waveBlocks, 256, 0, stream>>>(rowptr, adj, ET, asrc, adst, Hb, b1, l1b, Xb, N);

    // ---------- layer 2 ----------
    mfma_gemm<<<rowBlocks, 256, 0, stream>>>(Xb, BT2, Hb, asrc, adst, N, 256, 256, 0);
    gat_gather128<<<waveBlocks, 256, 0, stream>>>(rowptr, adj, ET, asrc, adst, Hb, b2, l2b, Xb, N);

    // ---------- layer 3 ----------
    mfma_gemm<<<rowBlocks, 256, 0, stream>>>(Xb, BT3, Hb, asrc, adst, N, 64, 80, 1);
    gat_gather40<<<waveBlocks, 256, 0, stream>>>(rowptr, adj, ET, asrc, adst, Hb, b3, l3b, (float*)d_out, N);
}

// Round 16
// 293.200 us; speedup vs baseline: 1.0259x; 1.0008x over previous
//
#include <hip/hip_runtime.h>
#include <math.h>

// 3-layer GAT. Round 16: XCD-bucketed deg histogram (deg lines single-XCD ->
// L2-resident atomics, kills ~24MB of line-writeback), csr_fill src loads
// reverted to scalar-on-hit (R15's always-int4 src was +22MB traffic).
// Structure: fused prep -> scans -> csr_fill -> per-layer GEMM+gather.

#define HEADS 4
#define FILLB 4096
#define NHISTB 4096

typedef __attribute__((ext_vector_type(8))) short short8v;   // 8 bf16
typedef __attribute__((ext_vector_type(4))) float float4v;   // 4 fp32 acc

__device__ __forceinline__ float lrelu(float v) { return v > 0.f ? v : 0.2f * v; }

__device__ __forceinline__ unsigned short f2bf(float f) {
    unsigned u = __float_as_uint(f);
    unsigned r = u + 0x7FFFu + ((u >> 16) & 1u);   // RNE
    return (unsigned short)(r >> 16);
}
__device__ __forceinline__ float bf2f(unsigned short u) {
    return __uint_as_float(((unsigned)u) << 16);
}

// ---------------- device bodies ----------------
__device__ void castX_body(const float* __restrict__ x, unsigned short* __restrict__ xb,
                           int n4, int i) {
    if (i >= n4) return;
    float4 v = *(const float4*)&x[(size_t)i * 4];
    ushort4 o;
    o.x = f2bf(v.x); o.y = f2bf(v.y); o.z = f2bf(v.z); o.w = f2bf(v.w);
    *(ushort4*)&xb[(size_t)i * 4] = o;
}

// XCD-bucketed histogram: block (grp, bucket) scans strided edge chunks,
// commits only dst in its bucket's node range -> deg lines single-XCD.
__device__ void hist_body(const int* __restrict__ dst, int E, int N,
                          int* __restrict__ deg, int grp, int bucket) {
    const int npb = (N + 7) >> 3;
    const int lo = bucket * npb;
    const int hi = (lo + npb < N) ? lo + npb : N;
    const int chunkSz = 2048;                 // 256 threads x 8 edges
    const int nchunks = (E + chunkSz - 1) / chunkSz;
    const int ngrp = NHISTB >> 3;
    for (int c = grp; c < nchunks; c += ngrp) {
        int base = c * chunkSz + (int)threadIdx.x * 8;
        if (base + 7 < E) {
            int4 a = *(const int4*)&dst[base];
            int4 b = *(const int4*)&dst[base + 4];
            int dd[8] = {a.x, a.y, a.z, a.w, b.x, b.y, b.z, b.w};
#pragma unroll
            for (int k = 0; k < 8; ++k)
                if (dd[k] >= lo && dd[k] < hi) atomicAdd(&deg[dd[k]], 1);
        } else {
            int lim = (base + 8 < E) ? base + 8 : E;
            for (int e = base; e < lim; ++e) {
                int d = dst[e];
                if (d >= lo && d < hi) atomicAdd(&deg[d], 1);
            }
        }
    }
}

// BT12: (256+64) rows x 128 k. rows 0..127 = W, 128..255 = LW, 256..259 = W@a_s,
// 260..263 = W@a_d, rest 0.
__device__ void packB12_body(const float* __restrict__ W, const float* __restrict__ LW,
                             const float* __restrict__ a_s, const float* __restrict__ a_d,
                             unsigned short* __restrict__ BT, int i) {
    if (i >= 320 * 128) return;
    int m = i >> 7, k = i & 127;
    float v = 0.f;
    if (m < 128) {
        v = W[(size_t)k * 128 + m];
    } else if (m < 256) {
        v = LW[(size_t)k * 128 + (m - 128)];
    } else if (m < 260) {
        int h = m - 256;
        for (int c = 0; c < 32; ++c)
            v = fmaf(W[(size_t)k * 128 + h * 32 + c], a_s[h * 32 + c], v);
    } else if (m < 264) {
        int h = m - 260;
        for (int c = 0; c < 32; ++c)
            v = fmaf(W[(size_t)k * 128 + h * 32 + c], a_d[h * 32 + c], v);
    }
    BT[i] = f2bf(v);
}

// BT3: 128 rows x 128 k. rows 0..39 = W3, 40..49 = LW3, 64..67 = W3@a_s,
// 68..71 = W3@a_d, rest 0.
__device__ void packB3_body(const float* __restrict__ W3, const float* __restrict__ LW3,
                            const float* __restrict__ a_s, const float* __restrict__ a_d,
                            unsigned short* __restrict__ BT, int i) {
    if (i >= 128 * 128) return;
    int m = i >> 7, k = i & 127;
    float v = 0.f;
    if (m < 40) {
        v = W3[(size_t)k * 40 + m];
    } else if (m < 50) {
        v = LW3[(size_t)k * 10 + (m - 40)];
    } else if (m >= 64 && m < 68) {
        int h = m - 64;
        for (int c = 0; c < 10; ++c)
            v = fmaf(W3[(size_t)k * 40 + h * 10 + c], a_s[h * 10 + c], v);
    } else if (m >= 68 && m < 72) {
        int h = m - 68;
        for (int c = 0; c < 10; ++c)
            v = fmaf(W3[(size_t)k * 40 + h * 10 + c], a_d[h * 10 + c], v);
    }
    BT[i] = f2bf(v);
}

// ---------------- K1: castX || hist(bucketed) || packB1 || packB2 || packB3 ----------------
__global__ __launch_bounds__(256) void prep_fused(
    const float* __restrict__ x, unsigned short* __restrict__ xb, int nCast, int n4,
    const int* __restrict__ ei, int E, int N, int* __restrict__ deg,
    const float* __restrict__ W1, const float* __restrict__ l1W,
    const float* __restrict__ a1s, const float* __restrict__ a1d, unsigned short* __restrict__ BT1,
    const float* __restrict__ W2, const float* __restrict__ l2W,
    const float* __restrict__ a2s, const float* __restrict__ a2d, unsigned short* __restrict__ BT2,
    const float* __restrict__ W3, const float* __restrict__ l3W,
    const float* __restrict__ a3s, const float* __restrict__ a3d, unsigned short* __restrict__ BT3)
{
    const int nPack12 = 160;   // 320*128/256
    const int bucket = blockIdx.x & 7;   // XCD-aligned regardless of section
    int b = blockIdx.x;
    if (b < nCast) {
        castX_body(x, xb, n4, b * 256 + threadIdx.x);
    } else if ((b -= nCast) < NHISTB) {
        hist_body(ei + E, E, N, deg, b >> 3, bucket);
    } else if ((b -= NHISTB) < nPack12) {
        packB12_body(W1, l1W, a1s, a1d, BT1, b * 256 + threadIdx.x);
    } else if ((b -= nPack12) < nPack12) {
        packB12_body(W2, l2W, a2s, a2d, BT2, b * 256 + threadIdx.x);
    } else {
        b -= nPack12;
        packB3_body(W3, l3W, a3s, a3d, BT3, b * 256 + threadIdx.x);
    }
}

// ---------------- XCD-bucketed CSR fill (int4 dst reads, src on hit) ----------------
__global__ __launch_bounds__(256) void csr_fill_bucket(
    const int* __restrict__ ei, int E, int N,
    const int* __restrict__ rowptr, int* __restrict__ cur,
    int* __restrict__ adj)
{
    const int bucket = blockIdx.x & 7;
    const int grp    = blockIdx.x >> 3;
    const int ngrp   = FILLB >> 3;
    const int npb    = (N + 7) >> 3;
    const int lo = bucket * npb;
    const int hi = (lo + npb < N) ? lo + npb : N;

    // self-loops for this bucket's nodes (first slot of each segment)
    for (int i = lo + grp * 256 + (int)threadIdx.x; i < hi; i += ngrp * 256)
        adj[rowptr[i]] = i;

    // edges: 1024-edge chunks; thread loads 4 contiguous dst (int4), src on hit
    const int chunkSz = 1024;
    const int nchunks = (E + chunkSz - 1) / chunkSz;
    const int* dstRow = ei + E;
    for (int c = grp; c < nchunks; c += ngrp) {
        int base = c * chunkSz + (int)threadIdx.x * 4;
        if (base + 3 < E) {
            int4 d4 = *(const int4*)&dstRow[base];
            int dd[4] = {d4.x, d4.y, d4.z, d4.w};
#pragma unroll
            for (int k = 0; k < 4; ++k) {
                int d = dd[k];
                if (d >= lo && d < hi) {
                    int pos = rowptr[d] + 1 + atomicAdd(&cur[d], 1);
                    adj[pos] = ei[base + k];
                }
            }
        } else {
            int lim = (base + 4 < E) ? base + 4 : E;
            for (int e = base; e < lim; ++e) {
                int d = dstRow[e];
                if (d >= lo && d < hi) {
                    int pos = rowptr[d] + 1 + atomicAdd(&cur[d], 1);
                    adj[pos] = ei[e];
                }
            }
        }
    }
}

// ---------------- MFMA GEMM, col-blocks looped in-block ----------------
__global__ __launch_bounds__(256) void mfma_gemm(const unsigned short* __restrict__ A,
                                                 const unsigned short* __restrict__ BT,
                                                 unsigned short* __restrict__ C,
                                                 float* __restrict__ asrc,
                                                 float* __restrict__ adst,
                                                 int nrows, int Mc, int Cstride,
                                                 int permStore) {
    const int wave = threadIdx.x >> 6;
    const int lane = threadIdx.x & 63;
    const int row0 = blockIdx.x * 64 + wave * 16;
    const int lrow = lane & 15;
    const int kgrp = lane >> 4;

    int arow = row0 + lrow;
    if (arow >= nrows) arow = nrows - 1;
    const unsigned short* Ap = A + (size_t)arow * 128 + kgrp * 8;

    short8v afrag[4];
#pragma unroll
    for (int t = 0; t < 4; ++t) afrag[t] = *(const short8v*)(Ap + t * 32);

    const int nDataBlk = Mc >> 6;
    for (int cb = 0; cb < nDataBlk; ++cb) {
        const unsigned short* Bp = BT + (size_t)(cb * 64 + lrow) * 128 + kgrp * 8;
        float4v acc[4] = {{0.f,0.f,0.f,0.f},{0.f,0.f,0.f,0.f},{0.f,0.f,0.f,0.f},{0.f,0.f,0.f,0.f}};
#pragma unroll
        for (int t = 0; t < 4; ++t) {
#pragma unroll
            for (int kk = 0; kk < 4; ++kk) {
                short8v b = *(const short8v*)(Bp + kk * 16 * 128 + t * 32);
                acc[kk] = __builtin_amdgcn_mfma_f32_16x16x32_bf16(afrag[t], b, acc[kk], 0, 0, 0);
            }
        }
#pragma unroll
        for (int r = 0; r < 4; ++r) {
            int row = row0 + kgrp * 4 + r;
            if (row >= nrows) continue;
            if (!permStore) {
                size_t base = (size_t)row * Cstride + cb * 64 + lrow;
                C[base]      = f2bf(acc[0][r]);
                C[base + 16] = f2bf(acc[1][r]);
                C[base + 32] = f2bf(acc[2][r]);
                C[base + 48] = f2bf(acc[3][r]);
            } else {
#pragma unroll
                for (int kk = 0; kk < 4; ++kk) {
                    int col = lrow + kk * 16;
                    int pos;
                    if (col < 40)      pos = (col / 5) * 8 + (col % 5);
                    else if (col < 50) pos = 64 + (col - 40);
                    else continue;
                    C[(size_t)row * 80 + pos] = f2bf(acc[kk][r]);
                }
            }
        }
    }

    // alpha block: 8 columns at BT rows Mc..Mc+7
    {
        const unsigned short* Bp = BT + (size_t)(Mc + lrow) * 128 + kgrp * 8;
        float4v acc0 = {0.f, 0.f, 0.f, 0.f};
#pragma unroll
        for (int t = 0; t < 4; ++t) {
            short8v b = *(const short8v*)(Bp + t * 32);
            acc0 = __builtin_amdgcn_mfma_f32_16x16x32_bf16(afrag[t], b, acc0, 0, 0, 0);
        }
        if (lrow < 8) {
            float* dst = (lrow < 4) ? asrc : adst;
            int hh = lrow & 3;
#pragma unroll
            for (int r = 0; r < 4; ++r) {
                int row = row0 + kgrp * 4 + r;
                if (row < nrows) dst[(size_t)row * 4 + hh] = acc0[r];
            }
        }
    }
}

// ---------------- scan kernels ----------------
__global__ void scan_block(const int* __restrict__ in, int* __restrict__ out,
                           int* __restrict__ bsum, int n) {
    __shared__ int tmp[256];
    int i = blockIdx.x * 256 + threadIdx.x;
    int v = (i < n) ? in[i] + 1 : 0;   // +1: self-loop slot
    tmp[threadIdx.x] = v;
    __syncthreads();
    for (int d = 1; d < 256; d <<= 1) {
        int t = (threadIdx.x >= d) ? tmp[threadIdx.x - d] : 0;
        __syncthreads();
        tmp[threadIdx.x] += t;
        __syncthreads();
    }
    if (i < n) out[i] = tmp[threadIdx.x] - v;
    if (threadIdx.x == 255) bsum[blockIdx.x] = tmp[255];
}

__global__ void scan_bsum(int* bsum, int nb) {
    __shared__ int tmp[256];
    int v = (threadIdx.x < nb) ? bsum[threadIdx.x] : 0;
    tmp[threadIdx.x] = v;
    __syncthreads();
    for (int d = 1; d < 256; d <<= 1) {
        int t = (threadIdx.x >= d) ? tmp[threadIdx.x - d] : 0;
        __syncthreads();
        tmp[threadIdx.x] += t;
        __syncthreads();
    }
    if (threadIdx.x < nb) bsum[threadIdx.x] = tmp[threadIdx.x] - v;
}

__global__ void scan_add(int* out, const int* __restrict__ bsum, int n) {
    int i = blockIdx.x * 256 + threadIdx.x;
    if (i < n) out[i] += bsum[blockIdx.x];
}

// ---------------- fused gather (HC=128): one wave per dst node ----------------
// 4 edge slots x 16 lanes x 8 channels; quad-unrolled.
__global__ __launch_bounds__(256) void gat_gather128(
    const int* __restrict__ rowptr, const int* __restrict__ adj, int ET,
    const float* __restrict__ asrc, const float* __restrict__ adst,
    const unsigned short* __restrict__ Hb,
    const float* __restrict__ bias, const float* __restrict__ lbias,
    unsigned short* __restrict__ xout, int n)
{
    int node = (blockIdx.x * 256 + threadIdx.x) >> 6;
    int lane = threadIdx.x & 63;
    if (node >= n) return;
    int beg = rowptr[node];
    int end = (node + 1 < n) ? rowptr[node + 1] : ET;

    int ep = lane >> 4;
    int q  = lane & 15;
    int c0 = q * 8;
    int h  = q >> 2;
    float adh = adst[(size_t)node * 4 + h];

    float accp = 0.f;
    float a[8];
#pragma unroll
    for (int k = 0; k < 8; ++k) a[k] = 0.f;

    int j = beg + ep;
    while (j < end) {
        int j1 = j + 4, j2 = j + 8, j3 = j + 12;
        bool v1 = j1 < end, v2 = j2 < end, v3 = j3 < end;
        int s0 = adj[j];
        int s1 = v1 ? adj[j1] : s0;
        int s2 = v2 ? adj[j2] : s0;
        int s3 = v3 ? adj[j3] : s0;
        float av0 = asrc[(size_t)s0 * 4 + h];
        float av1 = asrc[(size_t)s1 * 4 + h];
        float av2 = asrc[(size_t)s2 * 4 + h];
        float av3 = asrc[(size_t)s3 * 4 + h];
        short8v hv0 = *(const short8v*)&Hb[(size_t)s0 * 256 + c0];
        short8v hv1 = *(const short8v*)&Hb[(size_t)s1 * 256 + c0];
        short8v hv2 = *(const short8v*)&Hb[(size_t)s2 * 256 + c0];
        short8v hv3 = *(const short8v*)&Hb[(size_t)s3 * 256 + c0];
        float p0 = __expf(lrelu(av0 + adh));
        float p1 = v1 ? __expf(lrelu(av1 + adh)) : 0.f;
        float p2 = v2 ? __expf(lrelu(av2 + adh)) : 0.f;
        float p3 = v3 ? __expf(lrelu(av3 + adh)) : 0.f;
        accp += (p0 + p1) + (p2 + p3);
#pragma unroll
        for (int k = 0; k < 8; ++k) {
            float t0 = fmaf(p0, bf2f((unsigned short)hv0[k]), a[k]);
            float t1 = fmaf(p1, bf2f((unsigned short)hv1[k]), t0);
            float t2 = fmaf(p2, bf2f((unsigned short)hv2[k]), t1);
            a[k] = fmaf(p3, bf2f((unsigned short)hv3[k]), t2);
        }
        j += 16;
    }
#pragma unroll
    for (int off = 16; off <= 32; off <<= 1) {
        accp += __shfl_xor(accp, off);
#pragma unroll
        for (int k = 0; k < 8; ++k) a[k] += __shfl_xor(a[k], off);
    }

    if (ep == 0) {
        float inv = 1.f / (accp + 1e-16f);
        short8v lv = *(const short8v*)&Hb[(size_t)node * 256 + 128 + c0];
        unsigned short w[8];
#pragma unroll
        for (int k = 0; k < 8; ++k) {
            float v = a[k] * inv + bias[c0 + k] + bf2f((unsigned short)lv[k]) + lbias[c0 + k];
            v = v > 0.f ? v : __expf(v) - 1.f;
            w[k] = f2bf(v);
        }
        *(short8v*)&xout[(size_t)node * 128 + c0] = *(short8v*)w;
    }
}

// ---------------- fused gather layer 3 (C=10, mean over heads) ----------------
// 8 edge slots x 8 lanes x 5 channels; quad-unrolled. Hb3 stride 80 padded.
__global__ __launch_bounds__(256) void gat_gather40(
    const int* __restrict__ rowptr, const int* __restrict__ adj, int ET,
    const float* __restrict__ asrc, const float* __restrict__ adst,
    const unsigned short* __restrict__ Hb3,
    const float* __restrict__ bias, const float* __restrict__ lbias,
    float* __restrict__ out, int n)
{
    int node = (blockIdx.x * 256 + threadIdx.x) >> 6;
    int lane = threadIdx.x & 63;
    if (node >= n) return;
    int beg = rowptr[node];
    int end = (node + 1 < n) ? rowptr[node + 1] : ET;

    int slot = lane >> 3;
    int sub  = lane & 7;
    int h    = sub >> 1;
    float adh = adst[(size_t)node * 4 + h];

    float accp = 0.f;
    float a[5];
#pragma unroll
    for (int k = 0; k < 5; ++k) a[k] = 0.f;

    int j = beg + slot;
    while (j < end) {
        int j1 = j + 8, j2 = j + 16, j3 = j + 24;
        bool v1 = j1 < end, v2 = j2 < end, v3 = j3 < end;
        int s0 = adj[j];
        int s1 = v1 ? adj[j1] : s0;
        int s2 = v2 ? adj[j2] : s0;
        int s3 = v3 ? adj[j3] : s0;
        float av0 = asrc[(size_t)s0 * 4 + h];
        float av1 = asrc[(size_t)s1 * 4 + h];
        float av2 = asrc[(size_t)s2 * 4 + h];
        float av3 = asrc[(size_t)s3 * 4 + h];
        short8v hv0 = *(const short8v*)&Hb3[(size_t)s0 * 80 + sub * 8];
        short8v hv1 = *(const short8v*)&Hb3[(size_t)s1 * 80 + sub * 8];
        short8v hv2 = *(const short8v*)&Hb3[(size_t)s2 * 80 + sub * 8];
        short8v hv3 = *(const short8v*)&Hb3[(size_t)s3 * 80 + sub * 8];
        float p0 = __expf(lrelu(av0 + adh));
        float p1 = v1 ? __expf(lrelu(av1 + adh)) : 0.f;
        float p2 = v2 ? __expf(lrelu(av2 + adh)) : 0.f;
        float p3 = v3 ? __expf(lrelu(av3 + adh)) : 0.f;
        accp += (p0 + p1) + (p2 + p3);
#pragma unroll
        for (int k = 0; k < 5; ++k) {
            float t0 = fmaf(p0, bf2f((unsigned short)hv0[k]), a[k]);
            float t1 = fmaf(p1, bf2f((unsigned short)hv1[k]), t0);
            float t2 = fmaf(p2, bf2f((unsigned short)hv2[k]), t1);
            a[k] = fmaf(p3, bf2f((unsigned short)hv3[k]), t2);
        }
        j += 32;
    }
#pragma unroll
    for (int off = 8; off <= 32; off <<= 1) {
        accp += __shfl_xor(accp, off);
#pragma unroll
        for (int k = 0; k < 5; ++k) a[k] += __shfl_xor(a[k], off);
    }
    float inv = 0.25f / (accp + 1e-16f);
#pragma unroll
    for (int k = 0; k < 5; ++k) a[k] *= inv;
#pragma unroll
    for (int off = 2; off <= 4; off <<= 1) {
#pragma unroll
        for (int k = 0; k < 5; ++k) a[k] += __shfl_xor(a[k], off);
    }

    if (lane < 2) {
        int cc0 = sub * 5;
#pragma unroll
        for (int k = 0; k < 5; ++k) {
            float lin = bf2f(Hb3[(size_t)node * 80 + 64 + cc0 + k]);
            out[(size_t)node * 10 + cc0 + k] = a[k] + bias[cc0 + k] + lin + lbias[cc0 + k];
        }
    }
}

extern "C" void kernel_launch(void* const* d_in, const int* in_sizes, int n_in,
                              void* d_out, int out_size, void* d_ws, size_t ws_size,
                              hipStream_t stream) {
    const float* x   = (const float*)d_in[0];
    const int*   ei  = (const int*)d_in[1];
    const float* W1  = (const float*)d_in[2];
    const float* a1s = (const float*)d_in[3];
    const float* a1d = (const float*)d_in[4];
    const float* b1  = (const float*)d_in[5];
    const float* l1W = (const float*)d_in[6];
    const float* l1b = (const float*)d_in[7];
    const float* W2  = (const float*)d_in[8];
    const float* a2s = (const float*)d_in[9];
    const float* a2d = (const float*)d_in[10];
    const float* b2  = (const float*)d_in[11];
    const float* l2W = (const float*)d_in[12];
    const float* l2b = (const float*)d_in[13];
    const float* W3  = (const float*)d_in[14];
    const float* a3s = (const float*)d_in[15];
    const float* a3d = (const float*)d_in[16];
    const float* b3  = (const float*)d_in[17];
    const float* l3W = (const float*)d_in[18];
    const float* l3b = (const float*)d_in[19];

    const int N  = in_sizes[0] / 128;
    const int E  = in_sizes[1] / 2;
    const int ET = E + N;

    unsigned short* Xb  = (unsigned short*)d_ws;          // N*128 bf16
    unsigned short* Hb  = Xb + (size_t)N * 128;           // N*256 bf16 (layer3: N*80)
    unsigned short* BT1 = Hb + (size_t)N * 256;           // 320*128 bf16
    unsigned short* BT2 = BT1 + 320 * 128;                // 320*128 bf16
    unsigned short* BT3 = BT2 + 320 * 128;                // 128*128 bf16
    float* asrc = (float*)(BT3 + 128 * 128);              // N*4
    float* adst = asrc + (size_t)N * 4;                   // N*4
    int* deg    = (int*)(adst + (size_t)N * 4);           // N
    int* cur    = deg + N;                                // N (adjacent for one memset)
    int* rowptr = cur + N;                                // N
    int* bsum   = rowptr + N;                             // 256
    int* adj    = bsum + 256;                             // ET ints

    const int nScanBlocks = (N + 255) / 256;
    const int waveBlocks  = (N * 64 + 255) / 256;
    const int rowBlocks   = (N + 63) / 64;
    const int nCast = (N * 32 + 255) / 256;
    const int prepBlocks = nCast + NHISTB + 160 + 160 + 64;

    // ---------- prep: memset; K1 = castX || hist || packB x3; scans ----------
    hipMemsetAsync(deg, 0, (size_t)N * 2 * 4, stream);    // deg + cur
    prep_fused<<<prepBlocks, 256, 0, stream>>>(
        x, Xb, nCast, N * 32, ei, E, N, deg,
        W1, l1W, a1s, a1d, BT1, W2, l2W, a2s, a2d, BT2, W3, l3W, a3s, a3d, BT3);
    scan_block<<<nScanBlocks, 256, 0, stream>>>(deg, rowptr, bsum, N);
    scan_bsum<<<1, 256, 0, stream>>>(bsum, nScanBlocks);
    scan_add<<<nScanBlocks, 256, 0, stream>>>(rowptr, bsum, N);
    csr_fill_bucket<<<FILLB, 256, 0, stream>>>(ei, E, N, rowptr, cur, adj);

    // ---------- layer 1 ----------
    mfma_gemm<<<rowBlocks, 256, 0, stream>>>(Xb, BT1, Hb, asrc, adst, N, 256, 256, 0);
    gat_gather128<<<waveBlocks, 256, 0, stream>>>(rowptr, adj, ET, asrc, adst, Hb, b1, l1b, Xb, N);

    // ---------- layer 2 ----------
    mfma_gemm<<<rowBlocks, 256, 0, stream>>>(Xb, BT2, Hb, asrc, adst, N, 256, 256, 0);
    gat_gather128<<<waveBlocks, 256, 0, stream>>>(rowptr, adj, ET, asrc, adst, Hb, b2, l2b, Xb, N);

    // ---------- layer 3 ----------
    mfma_gemm<<<rowBlocks, 256, 0, stream>>>(Xb, BT3, Hb, asrc, adst, N, 64, 80, 1);
    gat_gather40<<<waveBlocks, 256, 0, stream>>>(rowptr, adj, ET, asrc, adst, Hb, b3, l3b, (float*)d_out, N);
}

// Round 17
// 274.044 us; speedup vs baseline: 1.0976x; 1.0699x over previous
//
#include <hip/hip_runtime.h>
#include <math.h>

// 3-layer GAT. Round 17: exact R12 configuration (measured best, 275.8us)
// + quad-unrolled gather40 (verified orthogonal win from R13/R14).
// K1 = castX || deg_hist || packB(L1,L2,L3); K2 = gemm(L1) then csr_fill
// (same kernel, blockIdx-ordered); standalone GEMMs L2/L3; quad gathers.

#define HEADS 4
#define FILLB 4096
#define FILL_U 4

typedef __attribute__((ext_vector_type(8))) short short8v;   // 8 bf16
typedef __attribute__((ext_vector_type(4))) float float4v;   // 4 fp32 acc

__device__ __forceinline__ float lrelu(float v) { return v > 0.f ? v : 0.2f * v; }

__device__ __forceinline__ unsigned short f2bf(float f) {
    unsigned u = __float_as_uint(f);
    unsigned r = u + 0x7FFFu + ((u >> 16) & 1u);   // RNE
    return (unsigned short)(r >> 16);
}
__device__ __forceinline__ float bf2f(unsigned short u) {
    return __uint_as_float(((unsigned)u) << 16);
}

// ---------------- device bodies ----------------
__device__ void castX_body(const float* __restrict__ x, unsigned short* __restrict__ xb,
                           int n4, int i) {
    if (i >= n4) return;
    float4 v = *(const float4*)&x[(size_t)i * 4];
    ushort4 o;
    o.x = f2bf(v.x); o.y = f2bf(v.y); o.z = f2bf(v.z); o.w = f2bf(v.w);
    *(ushort4*)&xb[(size_t)i * 4] = o;
}

__device__ void hist_body(const int* __restrict__ dst, int E, int* __restrict__ deg, int t) {
    int e = t * 4;
    if (e + 3 < E) {
        int4 d = *(const int4*)&dst[e];
        atomicAdd(&deg[d.x], 1);
        atomicAdd(&deg[d.y], 1);
        atomicAdd(&deg[d.z], 1);
        atomicAdd(&deg[d.w], 1);
    } else {
        for (; e < E; ++e) atomicAdd(&deg[dst[e]], 1);
    }
}

// BT12: (256+64) rows x 128 k. rows 0..127 = W, 128..255 = LW, 256..259 = W@a_s,
// 260..263 = W@a_d, rest 0.
__device__ void packB12_body(const float* __restrict__ W, const float* __restrict__ LW,
                             const float* __restrict__ a_s, const float* __restrict__ a_d,
                             unsigned short* __restrict__ BT, int i) {
    if (i >= 320 * 128) return;
    int m = i >> 7, k = i & 127;
    float v = 0.f;
    if (m < 128) {
        v = W[(size_t)k * 128 + m];
    } else if (m < 256) {
        v = LW[(size_t)k * 128 + (m - 128)];
    } else if (m < 260) {
        int h = m - 256;
        for (int c = 0; c < 32; ++c)
            v = fmaf(W[(size_t)k * 128 + h * 32 + c], a_s[h * 32 + c], v);
    } else if (m < 264) {
        int h = m - 260;
        for (int c = 0; c < 32; ++c)
            v = fmaf(W[(size_t)k * 128 + h * 32 + c], a_d[h * 32 + c], v);
    }
    BT[i] = f2bf(v);
}

// BT3: 128 rows x 128 k. rows 0..39 = W3, 40..49 = LW3, 64..67 = W3@a_s,
// 68..71 = W3@a_d, rest 0.
__device__ void packB3_body(const float* __restrict__ W3, const float* __restrict__ LW3,
                            const float* __restrict__ a_s, const float* __restrict__ a_d,
                            unsigned short* __restrict__ BT, int i) {
    if (i >= 128 * 128) return;
    int m = i >> 7, k = i & 127;
    float v = 0.f;
    if (m < 40) {
        v = W3[(size_t)k * 40 + m];
    } else if (m < 50) {
        v = LW3[(size_t)k * 10 + (m - 40)];
    } else if (m >= 64 && m < 68) {
        int h = m - 64;
        for (int c = 0; c < 10; ++c)
            v = fmaf(W3[(size_t)k * 40 + h * 10 + c], a_s[h * 10 + c], v);
    } else if (m >= 68 && m < 72) {
        int h = m - 68;
        for (int c = 0; c < 10; ++c)
            v = fmaf(W3[(size_t)k * 40 + h * 10 + c], a_d[h * 10 + c], v);
    }
    BT[i] = f2bf(v);
}

// GEMM body: 64-row block `bidx`; A frags register-resident; col-blocks looped.
__device__ void gemm_body(const unsigned short* __restrict__ A,
                          const unsigned short* __restrict__ BT,
                          unsigned short* __restrict__ C,
                          float* __restrict__ asrc, float* __restrict__ adst,
                          int nrows, int Mc, int Cstride, int permStore, int bidx) {
    const int wave = threadIdx.x >> 6;
    const int lane = threadIdx.x & 63;
    const int row0 = bidx * 64 + wave * 16;
    const int lrow = lane & 15;
    const int kgrp = lane >> 4;

    int arow = row0 + lrow;
    if (arow >= nrows) arow = nrows - 1;
    const unsigned short* Ap = A + (size_t)arow * 128 + kgrp * 8;

    short8v afrag[4];
#pragma unroll
    for (int t = 0; t < 4; ++t) afrag[t] = *(const short8v*)(Ap + t * 32);

    const int nDataBlk = Mc >> 6;
    for (int cb = 0; cb < nDataBlk; ++cb) {
        const unsigned short* Bp = BT + (size_t)(cb * 64 + lrow) * 128 + kgrp * 8;
        float4v acc[4] = {{0.f,0.f,0.f,0.f},{0.f,0.f,0.f,0.f},{0.f,0.f,0.f,0.f},{0.f,0.f,0.f,0.f}};
#pragma unroll
        for (int t = 0; t < 4; ++t) {
#pragma unroll
            for (int kk = 0; kk < 4; ++kk) {
                short8v b = *(const short8v*)(Bp + kk * 16 * 128 + t * 32);
                acc[kk] = __builtin_amdgcn_mfma_f32_16x16x32_bf16(afrag[t], b, acc[kk], 0, 0, 0);
            }
        }
#pragma unroll
        for (int r = 0; r < 4; ++r) {
            int row = row0 + kgrp * 4 + r;
            if (row >= nrows) continue;
            if (!permStore) {
                size_t base = (size_t)row * Cstride + cb * 64 + lrow;
                C[base]      = f2bf(acc[0][r]);
                C[base + 16] = f2bf(acc[1][r]);
                C[base + 32] = f2bf(acc[2][r]);
                C[base + 48] = f2bf(acc[3][r]);
            } else {
#pragma unroll
                for (int kk = 0; kk < 4; ++kk) {
                    int col = lrow + kk * 16;
                    int pos;
                    if (col < 40)      pos = (col / 5) * 8 + (col % 5);
                    else if (col < 50) pos = 64 + (col - 40);
                    else continue;
                    C[(size_t)row * 80 + pos] = f2bf(acc[kk][r]);
                }
            }
        }
    }

    // alpha block: 8 columns at BT rows Mc..Mc+7
    {
        const unsigned short* Bp = BT + (size_t)(Mc + lrow) * 128 + kgrp * 8;
        float4v acc0 = {0.f, 0.f, 0.f, 0.f};
#pragma unroll
        for (int t = 0; t < 4; ++t) {
            short8v b = *(const short8v*)(Bp + t * 32);
            acc0 = __builtin_amdgcn_mfma_f32_16x16x32_bf16(afrag[t], b, acc0, 0, 0, 0);
        }
        if (lrow < 8) {
            float* dst = (lrow < 4) ? asrc : adst;
            int hh = lrow & 3;
#pragma unroll
            for (int r = 0; r < 4; ++r) {
                int row = row0 + kgrp * 4 + r;
                if (row < nrows) dst[(size_t)row * 4 + hh] = acc0[r];
            }
        }
    }
}

// XCD-bucketed CSR fill body (bucket = bid&7 over dst ranges, FILLB blocks).
__device__ void fill_body(const int* __restrict__ ei, int E, int N,
                          const int* __restrict__ rowptr, int* __restrict__ cur,
                          int* __restrict__ adj, int bid) {
    const int bucket = bid & 7;
    const int grp    = bid >> 3;
    const int ngrp   = FILLB >> 3;
    const int npb    = (N + 7) >> 3;
    const int lo = bucket * npb;
    const int hi = (lo + npb < N) ? lo + npb : N;

    for (int i = lo + grp * 256 + (int)threadIdx.x; i < hi; i += ngrp * 256)
        adj[rowptr[i]] = i;

    const int chunkSz = 256 * FILL_U;
    const int nchunks = (E + chunkSz - 1) / chunkSz;
    const int* dstRow = ei + E;
    for (int c = grp; c < nchunks; c += ngrp) {
        int base = c * chunkSz + (int)threadIdx.x;
#pragma unroll
        for (int k = 0; k < FILL_U; ++k) {
            int e = base + k * 256;
            if (e < E) {
                int d = dstRow[e];
                if (d >= lo && d < hi) {
                    int pos = rowptr[d] + 1 + atomicAdd(&cur[d], 1);
                    adj[pos] = ei[e];
                }
            }
        }
    }
}

// ---------------- K1: castX || hist || packB1 || packB2 || packB3 ----------------
__global__ __launch_bounds__(256) void prep_fused(
    const float* __restrict__ x, unsigned short* __restrict__ xb, int nCast, int n4,
    const int* __restrict__ ei, int E, int* __restrict__ deg, int nHist,
    const float* __restrict__ W1, const float* __restrict__ l1W,
    const float* __restrict__ a1s, const float* __restrict__ a1d, unsigned short* __restrict__ BT1,
    const float* __restrict__ W2, const float* __restrict__ l2W,
    const float* __restrict__ a2s, const float* __restrict__ a2d, unsigned short* __restrict__ BT2,
    const float* __restrict__ W3, const float* __restrict__ l3W,
    const float* __restrict__ a3s, const float* __restrict__ a3d, unsigned short* __restrict__ BT3)
{
    const int nPack12 = 160;   // 320*128/256
    int b = blockIdx.x;
    if (b < nCast) {
        castX_body(x, xb, n4, b * 256 + threadIdx.x);
    } else if ((b -= nCast) < nHist) {
        hist_body(ei + E, E, deg, b * 256 + threadIdx.x);
    } else if ((b -= nHist) < nPack12) {
        packB12_body(W1, l1W, a1s, a1d, BT1, b * 256 + threadIdx.x);
    } else if ((b -= nPack12) < nPack12) {
        packB12_body(W2, l2W, a2s, a2d, BT2, b * 256 + threadIdx.x);
    } else {
        b -= nPack12;
        packB3_body(W3, l3W, a3s, a3d, BT3, b * 256 + threadIdx.x);
    }
}

// ---------------- K2: gemm(L1) || csr_fill (blockIdx-ordered, as R12) ----------------
__global__ __launch_bounds__(256) void gemm_fill_fused(
    const unsigned short* __restrict__ A, const unsigned short* __restrict__ BT,
    unsigned short* __restrict__ C, float* __restrict__ asrc, float* __restrict__ adst,
    int nrows, int rowBlocks,
    const int* __restrict__ ei, int E, int N,
    const int* __restrict__ rowptr, int* __restrict__ cur, int* __restrict__ adj)
{
    if ((int)blockIdx.x < rowBlocks)
        gemm_body(A, BT, C, asrc, adst, nrows, 256, 256, 0, blockIdx.x);
    else
        fill_body(ei, E, N, rowptr, cur, adj, blockIdx.x - rowBlocks);
}

// ---------------- standalone GEMM (layers 2,3) ----------------
__global__ __launch_bounds__(256) void mfma_gemm(const unsigned short* __restrict__ A,
                                                 const unsigned short* __restrict__ BT,
                                                 unsigned short* __restrict__ C,
                                                 float* __restrict__ asrc,
                                                 float* __restrict__ adst,
                                                 int nrows, int Mc, int Cstride,
                                                 int permStore) {
    gemm_body(A, BT, C, asrc, adst, nrows, Mc, Cstride, permStore, blockIdx.x);
}

// ---------------- scan kernels ----------------
__global__ void scan_block(const int* __restrict__ in, int* __restrict__ out,
                           int* __restrict__ bsum, int n) {
    __shared__ int tmp[256];
    int i = blockIdx.x * 256 + threadIdx.x;
    int v = (i < n) ? in[i] + 1 : 0;   // +1: self-loop slot
    tmp[threadIdx.x] = v;
    __syncthreads();
    for (int d = 1; d < 256; d <<= 1) {
        int t = (threadIdx.x >= d) ? tmp[threadIdx.x - d] : 0;
        __syncthreads();
        tmp[threadIdx.x] += t;
        __syncthreads();
    }
    if (i < n) out[i] = tmp[threadIdx.x] - v;
    if (threadIdx.x == 255) bsum[blockIdx.x] = tmp[255];
}

__global__ void scan_bsum(int* bsum, int nb) {
    __shared__ int tmp[256];
    int v = (threadIdx.x < nb) ? bsum[threadIdx.x] : 0;
    tmp[threadIdx.x] = v;
    __syncthreads();
    for (int d = 1; d < 256; d <<= 1) {
        int t = (threadIdx.x >= d) ? tmp[threadIdx.x - d] : 0;
        __syncthreads();
        tmp[threadIdx.x] += t;
        __syncthreads();
    }
    if (threadIdx.x < nb) bsum[threadIdx.x] = tmp[threadIdx.x] - v;
}

__global__ void scan_add(int* out, const int* __restrict__ bsum, int n) {
    int i = blockIdx.x * 256 + threadIdx.x;
    if (i < n) out[i] += bsum[blockIdx.x];
}

// ---------------- fused gather (HC=128): one wave per dst node ----------------
// 4 edge slots x 16 lanes x 8 channels; quad-unrolled.
__global__ __launch_bounds__(256) void gat_gather128(
    const int* __restrict__ rowptr, const int* __restrict__ adj, int ET,
    const float* __restrict__ asrc, const float* __restrict__ adst,
    const unsigned short* __restrict__ Hb,
    const float* __restrict__ bias, const float* __restrict__ lbias,
    unsigned short* __restrict__ xout, int n)
{
    int node = (blockIdx.x * 256 + threadIdx.x) >> 6;
    int lane = threadIdx.x & 63;
    if (node >= n) return;
    int beg = rowptr[node];
    int end = (node + 1 < n) ? rowptr[node + 1] : ET;

    int ep = lane >> 4;
    int q  = lane & 15;
    int c0 = q * 8;
    int h  = q >> 2;
    float adh = adst[(size_t)node * 4 + h];

    float accp = 0.f;
    float a[8];
#pragma unroll
    for (int k = 0; k < 8; ++k) a[k] = 0.f;

    int j = beg + ep;
    while (j < end) {
        int j1 = j + 4, j2 = j + 8, j3 = j + 12;
        bool v1 = j1 < end, v2 = j2 < end, v3 = j3 < end;
        int s0 = adj[j];
        int s1 = v1 ? adj[j1] : s0;
        int s2 = v2 ? adj[j2] : s0;
        int s3 = v3 ? adj[j3] : s0;
        float av0 = asrc[(size_t)s0 * 4 + h];
        float av1 = asrc[(size_t)s1 * 4 + h];
        float av2 = asrc[(size_t)s2 * 4 + h];
        float av3 = asrc[(size_t)s3 * 4 + h];
        short8v hv0 = *(const short8v*)&Hb[(size_t)s0 * 256 + c0];
        short8v hv1 = *(const short8v*)&Hb[(size_t)s1 * 256 + c0];
        short8v hv2 = *(const short8v*)&Hb[(size_t)s2 * 256 + c0];
        short8v hv3 = *(const short8v*)&Hb[(size_t)s3 * 256 + c0];
        float p0 = __expf(lrelu(av0 + adh));
        float p1 = v1 ? __expf(lrelu(av1 + adh)) : 0.f;
        float p2 = v2 ? __expf(lrelu(av2 + adh)) : 0.f;
        float p3 = v3 ? __expf(lrelu(av3 + adh)) : 0.f;
        accp += (p0 + p1) + (p2 + p3);
#pragma unroll
        for (int k = 0; k < 8; ++k) {
            float t0 = fmaf(p0, bf2f((unsigned short)hv0[k]), a[k]);
            float t1 = fmaf(p1, bf2f((unsigned short)hv1[k]), t0);
            float t2 = fmaf(p2, bf2f((unsigned short)hv2[k]), t1);
            a[k] = fmaf(p3, bf2f((unsigned short)hv3[k]), t2);
        }
        j += 16;
    }
#pragma unroll
    for (int off = 16; off <= 32; off <<= 1) {
        accp += __shfl_xor(accp, off);
#pragma unroll
        for (int k = 0; k < 8; ++k) a[k] += __shfl_xor(a[k], off);
    }

    if (ep == 0) {
        float inv = 1.f / (accp + 1e-16f);
        short8v lv = *(const short8v*)&Hb[(size_t)node * 256 + 128 + c0];
        unsigned short w[8];
#pragma unroll
        for (int k = 0; k < 8; ++k) {
            float v = a[k] * inv + bias[c0 + k] + bf2f((unsigned short)lv[k]) + lbias[c0 + k];
            v = v > 0.f ? v : __expf(v) - 1.f;
            w[k] = f2bf(v);
        }
        *(short8v*)&xout[(size_t)node * 128 + c0] = *(short8v*)w;
    }
}

// ---------------- fused gather layer 3 (C=10, mean over heads) ----------------
// 8 edge slots x 8 lanes x 5 channels; quad-unrolled. Hb3 stride 80 padded.
__global__ __launch_bounds__(256) void gat_gather40(
    const int* __restrict__ rowptr, const int* __restrict__ adj, int ET,
    const float* __restrict__ asrc, const float* __restrict__ adst,
    const unsigned short* __restrict__ Hb3,
    const float* __restrict__ bias, const float* __restrict__ lbias,
    float* __restrict__ out, int n)
{
    int node = (blockIdx.x * 256 + threadIdx.x) >> 6;
    int lane = threadIdx.x & 63;
    if (node >= n) return;
    int beg = rowptr[node];
    int end = (node + 1 < n) ? rowptr[node + 1] : ET;

    int slot = lane >> 3;
    int sub  = lane & 7;
    int h    = sub >> 1;
    float adh = adst[(size_t)node * 4 + h];

    float accp = 0.f;
    float a[5];
#pragma unroll
    for (int k = 0; k < 5; ++k) a[k] = 0.f;

    int j = beg + slot;
    while (j < end) {
        int j1 = j + 8, j2 = j + 16, j3 = j + 24;
        bool v1 = j1 < end, v2 = j2 < end, v3 = j3 < end;
        int s0 = adj[j];
        int s1 = v1 ? adj[j1] : s0;
        int s2 = v2 ? adj[j2] : s0;
        int s3 = v3 ? adj[j3] : s0;
        float av0 = asrc[(size_t)s0 * 4 + h];
        float av1 = asrc[(size_t)s1 * 4 + h];
        float av2 = asrc[(size_t)s2 * 4 + h];
        float av3 = asrc[(size_t)s3 * 4 + h];
        short8v hv0 = *(const short8v*)&Hb3[(size_t)s0 * 80 + sub * 8];
        short8v hv1 = *(const short8v*)&Hb3[(size_t)s1 * 80 + sub * 8];
        short8v hv2 = *(const short8v*)&Hb3[(size_t)s2 * 80 + sub * 8];
        short8v hv3 = *(const short8v*)&Hb3[(size_t)s3 * 80 + sub * 8];
        float p0 = __expf(lrelu(av0 + adh));
        float p1 = v1 ? __expf(lrelu(av1 + adh)) : 0.f;
        float p2 = v2 ? __expf(lrelu(av2 + adh)) : 0.f;
        float p3 = v3 ? __expf(lrelu(av3 + adh)) : 0.f;
        accp += (p0 + p1) + (p2 + p3);
#pragma unroll
        for (int k = 0; k < 5; ++k) {
            float t0 = fmaf(p0, bf2f((unsigned short)hv0[k]), a[k]);
            float t1 = fmaf(p1, bf2f((unsigned short)hv1[k]), t0);
            float t2 = fmaf(p2, bf2f((unsigned short)hv2[k]), t1);
            a[k] = fmaf(p3, bf2f((unsigned short)hv3[k]), t2);
        }
        j += 32;
    }
#pragma unroll
    for (int off = 8; off <= 32; off <<= 1) {
        accp += __shfl_xor(accp, off);
#pragma unroll
        for (int k = 0; k < 5; ++k) a[k] += __shfl_xor(a[k], off);
    }
    float inv = 0.25f / (accp + 1e-16f);
#pragma unroll
    for (int k = 0; k < 5; ++k) a[k] *= inv;
#pragma unroll
    for (int off = 2; off <= 4; off <<= 1) {
#pragma unroll
        for (int k = 0; k < 5; ++k) a[k] += __shfl_xor(a[k], off);
    }

    if (lane < 2) {
        int cc0 = sub * 5;
#pragma unroll
        for (int k = 0; k < 5; ++k) {
            float lin = bf2f(Hb3[(size_t)node * 80 + 64 + cc0 + k]);
            out[(size_t)node * 10 + cc0 + k] = a[k] + bias[cc0 + k] + lin + lbias[cc0 + k];
        }
    }
}

extern "C" void kernel_launch(void* const* d_in, const int* in_sizes, int n_in,
                              void* d_out, int out_size, void* d_ws, size_t ws_size,
                              hipStream_t stream) {
    const float* x   = (const float*)d_in[0];
    const int*   ei  = (const int*)d_in[1];
    const float* W1  = (const float*)d_in[2];
    const float* a1s = (const float*)d_in[3];
    const float* a1d = (const float*)d_in[4];
    const float* b1  = (const float*)d_in[5];
    const float* l1W = (const float*)d_in[6];
    const float* l1b = (const float*)d_in[7];
    const float* W2  = (const float*)d_in[8];
    const float* a2s = (const float*)d_in[9];
    const float* a2d = (const float*)d_in[10];
    const float* b2  = (const float*)d_in[11];
    const float* l2W = (const float*)d_in[12];
    const float* l2b = (const float*)d_in[13];
    const float* W3  = (const float*)d_in[14];
    const float* a3s = (const float*)d_in[15];
    const float* a3d = (const float*)d_in[16];
    const float* b3  = (const float*)d_in[17];
    const float* l3W = (const float*)d_in[18];
    const float* l3b = (const float*)d_in[19];

    const int N  = in_sizes[0] / 128;
    const int E  = in_sizes[1] / 2;
    const int ET = E + N;

    unsigned short* Xb  = (unsigned short*)d_ws;          // N*128 bf16
    unsigned short* Hb  = Xb + (size_t)N * 128;           // N*256 bf16 (layer3: N*80)
    unsigned short* BT1 = Hb + (size_t)N * 256;           // 320*128 bf16
    unsigned short* BT2 = BT1 + 320 * 128;                // 320*128 bf16
    unsigned short* BT3 = BT2 + 320 * 128;                // 128*128 bf16
    float* asrc = (float*)(BT3 + 128 * 128);              // N*4
    float* adst = asrc + (size_t)N * 4;                   // N*4
    int* deg    = (int*)(adst + (size_t)N * 4);           // N
    int* cur    = deg + N;                                // N (adjacent for one memset)
    int* rowptr = cur + N;                                // N
    int* bsum   = rowptr + N;                             // 256
    int* adj    = bsum + 256;                             // ET ints

    const int nScanBlocks = (N + 255) / 256;
    const int waveBlocks  = (N * 64 + 255) / 256;
    const int rowBlocks   = (N + 63) / 64;
    const int nCast = (N * 32 + 255) / 256;
    const int nHist = (E / 4 + 256) / 256;
    const int prepBlocks = nCast + nHist + 160 + 160 + 64;

    // ---------- prep: memset; K1 = castX || hist || packB x3 ----------
    hipMemsetAsync(deg, 0, (size_t)N * 2 * 4, stream);    // deg + cur
    prep_fused<<<prepBlocks, 256, 0, stream>>>(
        x, Xb, nCast, N * 32, ei, E, deg, nHist,
        W1, l1W, a1s, a1d, BT1, W2, l2W, a2s, a2d, BT2, W3, l3W, a3s, a3d, BT3);
    scan_block<<<nScanBlocks, 256, 0, stream>>>(deg, rowptr, bsum, N);
    scan_bsum<<<1, 256, 0, stream>>>(bsum, nScanBlocks);
    scan_add<<<nScanBlocks, 256, 0, stream>>>(rowptr, bsum, N);

    // ---------- layer 1 (gemm then csr_fill in one kernel, as R12) ----------
    gemm_fill_fused<<<rowBlocks + FILLB, 256, 0, stream>>>(
        Xb, BT1, Hb, asrc, adst, N, rowBlocks, ei, E, N, rowptr, cur, adj);
    gat_gather128<<<waveBlocks, 256, 0, stream>>>(rowptr, adj, ET, asrc, adst, Hb, b1, l1b, Xb, N);

    // ---------- layer 2 ----------
    mfma_gemm<<<rowBlocks, 256, 0, stream>>>(Xb, BT2, Hb, asrc, adst, N, 256, 256, 0);
    gat_gather128<<<waveBlocks, 256, 0, stream>>>(rowptr, adj, ET, asrc, adst, Hb, b2, l2b, Xb, N);

    // ---------- layer 3 ----------
    mfma_gemm<<<rowBlocks, 256, 0, stream>>>(Xb, BT3, Hb, asrc, adst, N, 64, 80, 1);
    gat_gather40<<<waveBlocks, 256, 0, stream>>>(rowptr, adj, ET, asrc, adst, Hb, b3, l3b, (float*)d_out, N);
}